// Round 8
// baseline (544.046 us; speedup 1.0000x reference)
//
#include <hip/hip_runtime.h>
#include <hip/hip_bf16.h>
#include <math.h>

#define B_N     4
#define L_N     2048
#define DMODEL  1024
#define DSTATE  128
#define DCONV   4
#define HEADDIM 64
#define CHUNK   256
#define DINNER  2048
#define NHEADS  32
#define CONVDIM 2304
#define DINPROJ 4384
#define NCHUNK  8
#define BL      (B_N*L_N)

typedef unsigned short ushort_t;
typedef unsigned int   uint_t;

typedef __attribute__((ext_vector_type(8))) short bf16x8;
typedef __attribute__((ext_vector_type(4))) float f32x4;

__device__ __forceinline__ float bfbits2f(ushort_t u){
    union { uint_t i; float f; } v; v.i = ((uint_t)u) << 16; return v.f;
}
__device__ __forceinline__ float bflo(uint_t u){
    union { uint_t i; float f; } v; v.i = u << 16; return v.f;
}
__device__ __forceinline__ float bfhi(uint_t u){
    union { uint_t i; float f; } v; v.i = u & 0xFFFF0000u; return v.f;
}
__device__ __forceinline__ ushort_t f2bf(float f){
    union { float f; uint_t i; } v; v.f = f;
    uint_t r = v.i + 0x7FFF + ((v.i >> 16) & 1);
    return (ushort_t)(r >> 16);
}
__device__ __forceinline__ void gload_lds16(const void* g, void* l){
    __builtin_amdgcn_global_load_lds(
        (const __attribute__((address_space(1))) unsigned int*)g,
        (__attribute__((address_space(3))) unsigned int*)l, 16, 0, 0);
}

// ---------------------------------------------------------------------------
// K0: f32 -> bf16 convert (8 elems/thread)
// ---------------------------------------------------------------------------
__global__ __launch_bounds__(256) void cvt_bf16(
    const float* __restrict__ in, ushort_t* __restrict__ out, int n8)
{
    int i = blockIdx.x*256 + threadIdx.x;
    if (i >= n8) return;
    const float4* p = (const float4*)(in + (size_t)i*8);
    float4 a = p[0], b = p[1];
    ushort_t o[8] = { f2bf(a.x), f2bf(a.y), f2bf(a.z), f2bf(a.w),
                      f2bf(b.x), f2bf(b.y), f2bf(b.z), f2bf(b.w) };
    *(uint4*)(out + (size_t)i*8) = *(const uint4*)o;
}

// ---------------------------------------------------------------------------
// K1: bf16 MFMA GEMM, C = A @ B^T. 256x128 tile, BK=32, 4 waves x 64 rows.
// 2-phase double-buffered LDS + XCD-aware bijective swizzle.
// EPI=0: f32 out [M][1024].
// EPI=1: in-proj split: cols<2048 -> z ; <4352 -> xbc_raw ; <4384 -> softplus dt.
// ---------------------------------------------------------------------------
template<int KDIM, int NTILES, int EPI>
__global__ __launch_bounds__(256) void gemm_bt_mfma(
    const ushort_t* __restrict__ A, const ushort_t* __restrict__ B,
    float* __restrict__ outf, ushort_t* __restrict__ z, ushort_t* __restrict__ xbc,
    const float* __restrict__ dt_bias, float* __restrict__ dtp)
{
    __shared__ __align__(16) ushort_t Asl[2][256*32];   // 32 KB
    __shared__ __align__(16) ushort_t Bsl[2][128*32];   // 16 KB

    // T1: bijective XCD swizzle (nwg % 8 == 0), n-fast decomposition
    int nwg = gridDim.x;
    int cpx = nwg >> 3;
    int lin = blockIdx.x;
    int work = (lin & 7)*cpx + (lin >> 3);
    int mtile = work / NTILES, ntile = work % NTILES;
    int m0 = mtile*256, n0 = ntile*128;

    int t = threadIdx.x;
    int l = t & 63, w = t >> 6;
    int l15 = l & 15, kb = l >> 4, l4 = l >> 4;
    int srow = t >> 2, skc = (t & 3)*8;

    f32x4 acc[4][8];
    #pragma unroll
    for (int m=0;m<4;m++){
        #pragma unroll
        for (int n=0;n<8;n++) acc[m][n] = (f32x4){0.f,0.f,0.f,0.f};
    }

    int br0 = n0 + srow, br1 = n0 + 64 + srow;
    if (EPI == 1){
        br0 = (br0 < DINPROJ) ? br0 : (DINPROJ-1);
        br1 = (br1 < DINPROJ) ? br1 : (DINPROJ-1);
    }

    auto stage = [&](int buf, int k0){
        #pragma unroll
        for (int seg=0; seg<4; seg++)
            gload_lds16(A + (size_t)(m0+seg*64+srow)*KDIM + k0 + skc,
                        &Asl[buf][seg*2048 + t*8]);
        gload_lds16(B + (size_t)br0*KDIM + k0 + skc, &Bsl[buf][t*8]);
        gload_lds16(B + (size_t)br1*KDIM + k0 + skc, &Bsl[buf][2048 + t*8]);
    };

    auto compute = [&](int cur){
        bf16x8 af[4], bfr[8];
        #pragma unroll
        for (int m=0;m<4;m++)
            af[m]  = *(const bf16x8*)&Asl[cur][(w*64 + m*16 + l15)*32 + kb*8];
        #pragma unroll
        for (int n=0;n<8;n++)
            bfr[n] = *(const bf16x8*)&Bsl[cur][(n*16 + l15)*32 + kb*8];
        __builtin_amdgcn_s_setprio(1);
        #pragma unroll
        for (int m=0;m<4;m++){
            #pragma unroll
            for (int n=0;n<8;n++)
                acc[m][n] = __builtin_amdgcn_mfma_f32_16x16x32_bf16(af[m], bfr[n], acc[m][n], 0, 0, 0);
        }
        __builtin_amdgcn_s_setprio(0);
    };

    stage(0, 0);
    __syncthreads();
    int cur = 0;

    for (int k0=32; k0<KDIM; k0+=32){
        stage(cur^1, k0);        // prefetch next K-tile, overlaps with compute
        compute(cur);
        __syncthreads();         // drains prefetch vmcnt + lgkm
        cur ^= 1;
    }
    compute(cur);                // tail

    #pragma unroll
    for (int m=0;m<4;m++){
        int rbase = m0 + w*64 + m*16 + l4*4;
        #pragma unroll
        for (int n=0;n<8;n++){
            int gcol = n0 + n*16 + l15;
            f32x4 v = acc[m][n];
            #pragma unroll
            for (int q=0;q<4;q++){
                int row = rbase + q;
                if (EPI == 0) {
                    outf[(size_t)row*DMODEL + gcol] = v[q];
                } else {
                    if (gcol < DINNER) {
                        z[(size_t)row*DINNER + gcol] = f2bf(v[q]);
                    } else if (gcol < DINNER + CONVDIM) {
                        xbc[(size_t)row*CONVDIM + (gcol - DINNER)] = f2bf(v[q]);
                    } else if (gcol < DINPROJ) {
                        int hh = gcol - (DINNER + CONVDIM);
                        float x = v[q] + dt_bias[hh];
                        float sp = (x > 15.f) ? x : log1pf(__expf(x));
                        int bb = row >> 11, ll = row & (L_N-1);
                        dtp[((size_t)bb*NHEADS + hh)*L_N + ll] = sp;
                    }
                }
            }
        }
    }
}

// ---------------------------------------------------------------------------
// K2: causal depthwise conv1d (width 4) + bias + SiLU
// ---------------------------------------------------------------------------
__global__ __launch_bounds__(256) void conv_silu(
    const __hip_bfloat16* __restrict__ xraw,
    const float* __restrict__ cw, const float* __restrict__ cb,
    __hip_bfloat16* __restrict__ xout)
{
    int idx = blockIdx.x*256 + threadIdx.x;
    if (idx >= BL*CONVDIM) return;
    int c  = idx % CONVDIM;
    int ml = idx / CONVDIM;
    int b  = ml / L_N;
    int l  = ml % L_N;
    const ushort_t* xr = (const ushort_t*)xraw;
    float acc = cb[c];
    #pragma unroll
    for (int k=0;k<DCONV;k++){
        int li = l - (DCONV-1) + k;
        if (li >= 0)
            acc += cw[c*DCONV + k] * bfbits2f(xr[((size_t)b*L_N + li)*CONVDIM + c]);
    }
    float s = acc / (1.f + __expf(-acc));
    xout[idx] = __float2bfloat16(s);
}

// ---------------------------------------------------------------------------
// K3: dA = dt*A; inclusive cumsum within each chunk  (block per (b,h,c))
// ---------------------------------------------------------------------------
__global__ __launch_bounds__(256) void dt_cumsum(
    const float* __restrict__ dtp, const float* __restrict__ A_log,
    float* __restrict__ dAcs)
{
    int blk = blockIdx.x;
    int c  = blk % NCHUNK;
    int bh = blk / NCHUNK;     // b*32 + h
    int h  = bh & (NHEADS-1);
    int t  = threadIdx.x;
    float A = -__expf(A_log[h]);
    __shared__ float sm[CHUNK];
    float v = dtp[(size_t)bh*L_N + c*CHUNK + t] * A;
    sm[t] = v;
    __syncthreads();
    for (int off=1; off<CHUNK; off<<=1){
        float add = (t >= off) ? sm[t-off] : 0.f;
        __syncthreads();
        sm[t] += add;
        __syncthreads();
    }
    dAcs[(size_t)bh*L_N + c*CHUNK + t] = sm[t];
}

// ---------------------------------------------------------------------------
// K6: states[p][n] = sum_j (coef_j*x[j,p]) * B[j,n]  via MFMA.
// ---------------------------------------------------------------------------
__device__ __forceinline__ int swz264(int row, int col){   // col in ushorts
    return row*264 + (col ^ (((row>>3)&7)<<3));
}

__global__ __launch_bounds__(256) void ssd_states_mfma(
    const __hip_bfloat16* __restrict__ xbc,
    const float* __restrict__ dtp, const float* __restrict__ dAcs,
    float* __restrict__ states)
{
    __shared__ __align__(16) ushort_t xdT[64*264];    // 33.8 KB
    __shared__ __align__(16) ushort_t BT[128*264];    // 67.6 KB
    __shared__ float coef_s[CHUNK];
    int bc = blockIdx.x, h = blockIdx.y;
    int b = bc >> 3, c = bc & 7;
    int t = threadIdx.x;
    int l = t & 63, w = t >> 6;
    int l15 = l & 15, l4 = l >> 4;
    const ushort_t* xb = (const ushort_t*)xbc;
    const size_t rowbase = (size_t)bc*CHUNK*CONVDIM;

    size_t dbase = ((size_t)b*NHEADS + h)*L_N + c*CHUNK;
    float last = dAcs[dbase + CHUNK-1];
    coef_s[t] = __expf(last - dAcs[dbase + t]) * dtp[dbase + t];
    __syncthreads();

    // stage xdT[p][j] = coef_j * x[j][p]  (bf16)
    #pragma unroll
    for (int ps=0; ps<8; ps++){
        int idx = ps*256 + t;
        int j = idx >> 3, p0 = (idx & 7)*8;
        float cj = coef_s[j];
        bf16x8 v = *(const bf16x8*)&xb[rowbase + (size_t)j*CONVDIM + h*HEADDIM + p0];
        #pragma unroll
        for (int e=0;e<8;e++)
            xdT[swz264(p0+e, j)] = f2bf(cj * bfbits2f(((const ushort_t*)&v)[e]));
    }
    // stage BT[n][j] = B[j][n]
    #pragma unroll
    for (int ps=0; ps<16; ps++){
        int idx = ps*256 + t;
        int j = idx >> 4, n0 = (idx & 15)*8;
        bf16x8 v = *(const bf16x8*)&xb[rowbase + (size_t)j*CONVDIM + DINNER + n0];
        #pragma unroll
        for (int e=0;e<8;e++)
            BT[swz264(n0+e, j)] = ((const ushort_t*)&v)[e];
    }
    __syncthreads();

    f32x4 acc[4][2];
    #pragma unroll
    for (int pf=0;pf<4;pf++){
        #pragma unroll
        for (int nf=0;nf<2;nf++) acc[pf][nf] = (f32x4){0.f,0.f,0.f,0.f};
    }

    #pragma unroll
    for (int k=0;k<8;k++){
        bf16x8 af[4], bv[2];
        #pragma unroll
        for (int pf=0;pf<4;pf++)
            af[pf] = *(const bf16x8*)&xdT[swz264(pf*16 + l15, k*32 + l4*8)];
        #pragma unroll
        for (int nf=0;nf<2;nf++)
            bv[nf] = *(const bf16x8*)&BT[swz264(w*32 + nf*16 + l15, k*32 + l4*8)];
        #pragma unroll
        for (int pf=0;pf<4;pf++){
            #pragma unroll
            for (int nf=0;nf<2;nf++)
                acc[pf][nf] = __builtin_amdgcn_mfma_f32_16x16x32_bf16(af[pf], bv[nf], acc[pf][nf], 0, 0, 0);
        }
    }

    float* sb = states + (size_t)(bc*NHEADS + h)*HEADDIM*DSTATE;
    #pragma unroll
    for (int pf=0;pf<4;pf++){
        #pragma unroll
        for (int nf=0;nf<2;nf++){
            #pragma unroll
            for (int q=0;q<4;q++){
                int p = pf*16 + l4*4 + q;
                int n = w*32 + nf*16 + l15;
                sb[(size_t)p*DSTATE + n] = acc[pf][nf][q];
            }
        }
    }
}

// ---------------------------------------------------------------------------
// K7: inter-chunk scan (sequential over 8 chunks), in-place: states -> prev
// ---------------------------------------------------------------------------
__global__ __launch_bounds__(256) void scan_states(
    float* __restrict__ states, const float* __restrict__ dAcs)
{
    int idx = blockIdx.x*256 + threadIdx.x;   // ((b*32+h)*64+p)*128+n
    int n  = idx & 127;
    int p  = (idx >> 7) & 63;
    int bh = idx >> 13;
    int b  = bh >> 5, h = bh & 31;
    float carry = 0.f;
    for (int c=0;c<NCHUNK;c++){
        size_t off = (((size_t)((b*NCHUNK + c)*NHEADS + h))*HEADDIM + p)*DSTATE + n;
        float s = states[off];
        states[off] = carry;
        float cd = __expf(dAcs[((size_t)b*NHEADS + h)*L_N + c*CHUNK + (CHUNK-1)]);
        carry = carry * cd + s;
    }
}

// ---------------------------------------------------------------------------
// K5: fused MFMA SSD: yh = exp(da_i)*(C@prev^T) + (W@x^T) + D*x
// ---------------------------------------------------------------------------
__global__ __launch_bounds__(256, 1) void ssd_mfma(
    const __hip_bfloat16* __restrict__ xbc,
    const float* __restrict__ dtp, const float* __restrict__ dAcs,
    const float* __restrict__ states, const float* __restrict__ D_param,
    float* __restrict__ yh)
{
    __shared__ __align__(16) ushort_t Cs[256*136];   // C tile,  pad->conflict-free
    __shared__ __align__(16) ushort_t Bs[64*136];    // B panel / prev (reused)
    __shared__ __align__(16) ushort_t Ws[256*72];    // W panel (bf16)
    __shared__ __align__(16) ushort_t xdT[64*264];   // x^T: xdT[p][j] = x[j,p]
    __shared__ float da_s[CHUNK];
    __shared__ float dt_s[CHUNK];

    int bc = blockIdx.x, h = blockIdx.y;
    int b = bc >> 3, c = bc & 7;
    int t = threadIdx.x;
    int l = t & 63, w = t >> 6;
    int l15 = l & 15, l4 = l >> 4;

    const ushort_t* xb = (const ushort_t*)xbc;
    const size_t rowbase = (size_t)bc*CHUNK*CONVDIM;

    da_s[t] = dAcs[((size_t)b*NHEADS + h)*L_N + c*CHUNK + t];
    dt_s[t] = dtp[((size_t)b*NHEADS + h)*L_N + c*CHUNK + t];

    // stage C (cols 2176..2303) -> Cs[256][136]
    #pragma unroll
    for (int ps=0; ps<16; ps++){
        int idx = ps*256 + t;
        int r = idx >> 4, ck = idx & 15;
        *(uint4*)&Cs[r*136 + ck*8] =
            *(const uint4*)&xb[rowbase + (size_t)r*CONVDIM + (DINNER+DSTATE) + ck*8];
    }
    // stage x^T (cols h*64..): xdT[p][j] = x[j,p]
    #pragma unroll
    for (int ps=0; ps<8; ps++){
        int idx = ps*256 + t;
        int j = idx >> 3, p0 = (idx & 7)*8;
        bf16x8 v = *(const bf16x8*)&xb[rowbase + (size_t)j*CONVDIM + h*HEADDIM + p0];
        #pragma unroll
        for (int e=0;e<8;e++) xdT[(p0+e)*264 + j] = ((const ushort_t*)&v)[e];
    }
    // stage prev (f32 [64][128]) -> Bs bf16 [64][136]
    const float* sbp = states + (size_t)(bc*NHEADS + h)*HEADDIM*DSTATE;
    #pragma unroll
    for (int ps=0; ps<8; ps++){
        int idx = ps*256 + t;
        int p = idx >> 5, n0 = (idx & 31)*4;
        float4 v = *(const float4*)&sbp[p*DSTATE + n0];
        ushort_t o[4] = { f2bf(v.x), f2bf(v.y), f2bf(v.z), f2bf(v.w) };
        *(uint2*)&Bs[p*136 + n0] = *(const uint2*)o;
    }
    __syncthreads();

    f32x4 yacc[4][4];
    #pragma unroll
    for (int m=0;m<4;m++){
        #pragma unroll
        for (int np=0;np<4;np++) yacc[m][np] = (f32x4){0.f,0.f,0.f,0.f};
    }

    // ---- Y_off = C @ prev^T  (K = DSTATE = 128, 4 k-steps)
    #pragma unroll
    for (int k=0;k<4;k++){
        bf16x8 bfk[4];
        #pragma unroll
        for (int np=0;np<4;np++)
            bfk[np] = *(const bf16x8*)&Bs[(np*16 + l15)*136 + k*32 + l4*8];
        #pragma unroll
        for (int m=0;m<4;m++){
            int i0 = (m*4 + w)*16;
            bf16x8 af = *(const bf16x8*)&Cs[(i0 + l15)*136 + k*32 + l4*8];
            #pragma unroll
            for (int np=0;np<4;np++)
                yacc[m][np] = __builtin_amdgcn_mfma_f32_16x16x32_bf16(af, bfk[np], yacc[m][np], 0, 0, 0);
        }
    }
    // scale rows by exp(da_i)
    #pragma unroll
    for (int m=0;m<4;m++){
        int i0 = (m*4 + w)*16;
        #pragma unroll
        for (int q=0;q<4;q++){
            float e = __expf(da_s[i0 + l4*4 + q]);
            #pragma unroll
            for (int np=0;np<4;np++) yacc[m][np][q] *= e;
        }
    }
    __syncthreads();   // prev use done; Bs will be overwritten

    // ---- Y_diag panels (j in blocks of 64)
    for (int jp=0; jp<4; jp++){
        #pragma unroll
        for (int ps=0; ps<4; ps++){
            int idx = ps*256 + t;
            int jr = idx >> 4, ck = idx & 15;
            *(uint4*)&Bs[jr*136 + ck*8] =
                *(const uint4*)&xb[rowbase + (size_t)(jp*64+jr)*CONVDIM + DINNER + ck*8];
        }
        __syncthreads();

        bf16x8 bfx[4][2];
        #pragma unroll
        for (int np=0;np<4;np++){
            #pragma unroll
            for (int ks=0;ks<2;ks++)
                bfx[np][ks] = *(const bf16x8*)&xdT[(np*16 + l15)*264 + jp*64 + ks*32 + l4*8];
        }

        #pragma unroll
        for (int m=0;m<4;m++){
            int i0 = (m*4 + w)*16;
            int imax = i0 + 15;
            int kmaxY = (jp*64 <= imax ? 1 : 0) + (jp*64+32 <= imax ? 1 : 0);
            if (kmaxY == 0) continue;          // wave-uniform
            int nmax = 2*kmaxY;

            // P = C @ B^T for this (m, panel)
            f32x4 pacc[4];
            #pragma unroll
            for (int n=0;n<4;n++) pacc[n] = (f32x4){0.f,0.f,0.f,0.f};
            #pragma unroll
            for (int k=0;k<4;k++){
                bf16x8 af = *(const bf16x8*)&Cs[(i0 + l15)*136 + k*32 + l4*8];
                #pragma unroll
                for (int n=0;n<4;n++){
                    if (jp*64 + n*16 <= imax){
                        bf16x8 bfB = *(const bf16x8*)&Bs[(n*16 + l15)*136 + k*32 + l4*8];
                        pacc[n] = __builtin_amdgcn_mfma_f32_16x16x32_bf16(af, bfB, pacc[n], 0, 0, 0);
                    }
                }
            }
            // W = mask * exp(da_i-da_j) * dt_j * P  -> bf16 -> Ws
            float dai[4];
            #pragma unroll
            for (int q=0;q<4;q++) dai[q] = da_s[i0 + l4*4 + q];
            #pragma unroll
            for (int n=0;n<4;n++){
                if (n < nmax){
                    int jcol = jp*64 + n*16 + l15;
                    float daj = da_s[jcol], dtj = dt_s[jcol];
                    #pragma unroll
                    for (int q=0;q<4;q++){
                        int i = i0 + l4*4 + q;
                        float wv = 0.f;
                        if (jcol <= i) wv = __expf(dai[q] - daj) * dtj * pacc[n][q];
                        Ws[i*72 + n*16 + l15] = f2bf(wv);
                    }
                }
            }
            // Y += W @ x^T  (k over the 64-wide panel, 2 k-steps)
            #pragma unroll
            for (int ks=0;ks<2;ks++){
                if (ks < kmaxY){
                    bf16x8 wfA = *(const bf16x8*)&Ws[(i0 + l15)*72 + ks*32 + l4*8];
                    #pragma unroll
                    for (int np=0;np<4;np++)
                        yacc[m][np] = __builtin_amdgcn_mfma_f32_16x16x32_bf16(wfA, bfx[np][ks], yacc[m][np], 0, 0, 0);
                }
            }
        }
        __syncthreads();
    }

    // ---- epilogue: + D*x, store
    float Dh = D_param[h];
    #pragma unroll
    for (int m=0;m<4;m++){
        int i0 = (m*4 + w)*16;
        #pragma unroll
        for (int np=0;np<4;np++){
            int p = np*16 + l15;
            #pragma unroll
            for (int q=0;q<4;q++){
                int i = i0 + l4*4 + q;
                float xv = bfbits2f(xdT[p*264 + i]);
                yh[((size_t)bc*CHUNK + i)*DINNER + h*HEADDIM + p] = yacc[m][np][q] + Dh*xv;
            }
        }
    }
}

// ---------------------------------------------------------------------------
// K9: g = yh * silu(z); RMSNorm(g)*norm_w  -> bf16 g  (block per token row)
// ---------------------------------------------------------------------------
__global__ __launch_bounds__(256) void gate_norm(
    const float* __restrict__ yh, const __hip_bfloat16* __restrict__ z,
    const float* __restrict__ norm_w, __hip_bfloat16* __restrict__ g)
{
    int row = blockIdx.x;
    int t = threadIdx.x;
    const float* yr = yh + (size_t)row*DINNER;
    const ushort_t* zr = (const ushort_t*)z + (size_t)row*DINNER;
    float v[8];
    float ss = 0.f;
    #pragma unroll
    for (int r=0;r<8;r++){
        int d = r*256 + t;
        float zv = bfbits2f(zr[d]);
        float gv = yr[d] * (zv / (1.f + __expf(-zv)));
        v[r] = gv; ss += gv*gv;
    }
    #pragma unroll
    for (int off=32; off>=1; off>>=1) ss += __shfl_xor(ss, off);
    __shared__ float red[4];
    if ((t & 63) == 0) red[t >> 6] = ss;
    __syncthreads();
    float tot = red[0]+red[1]+red[2]+red[3];
    float scale = rsqrtf(tot * (1.f/DINNER) + 1e-5f);
    __hip_bfloat16* gr = g + (size_t)row*DINNER;
    #pragma unroll
    for (int r=0;r<8;r++){
        int d = r*256 + t;
        gr[d] = __float2bfloat16(v[r]*scale*norm_w[d]);
    }
}

// ---------------------------------------------------------------------------
extern "C" void kernel_launch(void* const* d_in, const int* in_sizes, int n_in,
                              void* d_out, int out_size, void* d_ws, size_t ws_size,
                              hipStream_t stream)
{
    const float* u       = (const float*)d_in[0];
    const float* W_in    = (const float*)d_in[1];
    const float* conv_w  = (const float*)d_in[2];
    const float* conv_b  = (const float*)d_in[3];
    const float* dt_bias = (const float*)d_in[4];
    const float* A_log   = (const float*)d_in[5];
    const float* D_param = (const float*)d_in[6];
    const float* norm_w  = (const float*)d_in[7];
    const float* W_out   = (const float*)d_in[8];
    float* out = (float*)d_out;

    char* p = (char*)d_ws;
    auto take = [&](size_t n){ char* r = p; p += (n + 255) & ~(size_t)255; return r; };

    __hip_bfloat16* z       = (__hip_bfloat16*)take((size_t)BL*DINNER*2);
    __hip_bfloat16* xbc_raw = (__hip_bfloat16*)take((size_t)BL*CONVDIM*2);
    __hip_bfloat16* xbc     = (__hip_bfloat16*)take((size_t)BL*CONVDIM*2);
    float* dtp     = (float*)take((size_t)BL*NHEADS*4);
    float* dAcs    = (float*)take((size_t)BL*NHEADS*4);
    float* states  = (float*)take((size_t)B_N*NCHUNK*NHEADS*HEADDIM*DSTATE*4);
    float* yh      = (float*)take((size_t)BL*DINNER*4);
    ushort_t* u_bf  = (ushort_t*)take((size_t)BL*DMODEL*2);
    ushort_t* Wi_bf = (ushort_t*)take((size_t)DINPROJ*DMODEL*2);
    ushort_t* Wo_bf = (ushort_t*)take((size_t)DMODEL*DINNER*2);
    __hip_bfloat16* g = z;   // alias: z dead after gate_norm's elementwise read

    // converts
    cvt_bf16<<<dim3((BL*DMODEL/8 + 255)/256), 256, 0, stream>>>(u, u_bf, BL*DMODEL/8);
    cvt_bf16<<<dim3((DINPROJ*DMODEL/8 + 255)/256), 256, 0, stream>>>(W_in, Wi_bf, DINPROJ*DMODEL/8);
    cvt_bf16<<<dim3((DMODEL*DINNER/8 + 255)/256), 256, 0, stream>>>(W_out, Wo_bf, DMODEL*DINNER/8);

    // in-proj: z + xBC + dt (M tiles 8192/256=32, N tiles 35 -> 1120 wg)
    gemm_bt_mfma<DMODEL,35,1><<<dim3(32*35), 256, 0, stream>>>(
        u_bf, Wi_bf, nullptr, (ushort_t*)z, (ushort_t*)xbc_raw, dt_bias, dtp);

    conv_silu<<<dim3((BL*CONVDIM)/256), 256, 0, stream>>>(xbc_raw, conv_w, conv_b, xbc);
    dt_cumsum<<<dim3(B_N*NHEADS*NCHUNK), 256, 0, stream>>>(dtp, A_log, dAcs);
    ssd_states_mfma<<<dim3(B_N*NCHUNK, NHEADS), 256, 0, stream>>>(xbc, dtp, dAcs, states);
    scan_states<<<dim3((B_N*NHEADS*HEADDIM*DSTATE)/256), 256, 0, stream>>>(states, dAcs);
    ssd_mfma<<<dim3(B_N*NCHUNK, NHEADS), 256, 0, stream>>>(xbc, dtp, dAcs, states, D_param, yh);
    gate_norm<<<dim3(BL), 256, 0, stream>>>(yh, z, norm_w, g);

    // out-proj: M tiles 32, N tiles 8 -> 256 wg
    gemm_bt_mfma<DINNER,8,0><<<dim3(32*8), 256, 0, stream>>>(
        (const ushort_t*)g, Wo_bf, out, nullptr, nullptr, nullptr, nullptr);
}

// Round 9
// 503.563 us; speedup vs baseline: 1.0804x; 1.0804x over previous
//
#include <hip/hip_runtime.h>
#include <hip/hip_bf16.h>
#include <math.h>

#define B_N     4
#define L_N     2048
#define DMODEL  1024
#define DSTATE  128
#define DCONV   4
#define HEADDIM 64
#define CHUNK   256
#define DINNER  2048
#define NHEADS  32
#define CONVDIM 2304
#define DINPROJ 4384
#define NCHUNK  8
#define BL      (B_N*L_N)

typedef unsigned short ushort_t;
typedef unsigned int   uint_t;

typedef __attribute__((ext_vector_type(8))) short bf16x8;
typedef __attribute__((ext_vector_type(4))) float f32x4;

__device__ __forceinline__ float bfbits2f(ushort_t u){
    union { uint_t i; float f; } v; v.i = ((uint_t)u) << 16; return v.f;
}
__device__ __forceinline__ ushort_t f2bf(float f){
    union { float f; uint_t i; } v; v.f = f;
    uint_t r = v.i + 0x7FFF + ((v.i >> 16) & 1);
    return (ushort_t)(r >> 16);
}
__device__ __forceinline__ void gload_lds16(const void* g, void* l){
    __builtin_amdgcn_global_load_lds(
        (const __attribute__((address_space(1))) unsigned int*)g,
        (__attribute__((address_space(3))) unsigned int*)l, 16, 0, 0);
}

// ---------------------------------------------------------------------------
// K0: f32 -> bf16 convert (8 elems/thread)
// ---------------------------------------------------------------------------
__global__ __launch_bounds__(256) void cvt_bf16(
    const float* __restrict__ in, ushort_t* __restrict__ out, int n8)
{
    int i = blockIdx.x*256 + threadIdx.x;
    if (i >= n8) return;
    const float4* p = (const float4*)(in + (size_t)i*8);
    float4 a = p[0], b = p[1];
    ushort_t o[8] = { f2bf(a.x), f2bf(a.y), f2bf(a.z), f2bf(a.w),
                      f2bf(b.x), f2bf(b.y), f2bf(b.z), f2bf(b.w) };
    *(uint4*)(out + (size_t)i*8) = *(const uint4*)o;
}

// ---------------------------------------------------------------------------
// K1: bf16 MFMA GEMM, C = A @ B^T. 128x128 tile, BK=32, 4 waves.
// 2-phase double-buffered LDS + XCD-aware bijective swizzle. (R7 config)
// ---------------------------------------------------------------------------
template<int KDIM, int NTILES, int EPI>
__global__ __launch_bounds__(256) void gemm_bt_mfma(
    const ushort_t* __restrict__ A, const ushort_t* __restrict__ B,
    float* __restrict__ outf, ushort_t* __restrict__ z, ushort_t* __restrict__ xbc,
    const float* __restrict__ dt_bias, float* __restrict__ dtp)
{
    __shared__ __align__(16) ushort_t Asl[2][128*32];
    __shared__ __align__(16) ushort_t Bsl[2][128*32];

    int nwg = gridDim.x;
    int cpx = nwg >> 3;
    int lin = blockIdx.x;
    int work = (lin & 7)*cpx + (lin >> 3);
    int mtile = work / NTILES, ntile = work % NTILES;
    int m0 = mtile*128, n0 = ntile*128;

    int t = threadIdx.x;
    int l = t & 63, w = t >> 6;
    int wr = w >> 1, wc = w & 1;
    int lr16 = l & 15, kb = l >> 4;
    int srow = t >> 2, skc = (t & 3)*8;

    f32x4 acc[4][4];
    #pragma unroll
    for (int m=0;m<4;m++){
        #pragma unroll
        for (int n=0;n<4;n++) acc[m][n] = (f32x4){0.f,0.f,0.f,0.f};
    }

    int br0 = n0 + srow, br1 = n0 + 64 + srow;
    if (EPI == 1){
        br0 = (br0 < DINPROJ) ? br0 : (DINPROJ-1);
        br1 = (br1 < DINPROJ) ? br1 : (DINPROJ-1);
    }

    auto stage = [&](int buf, int k0){
        gload_lds16(A + (size_t)(m0+srow)*KDIM + k0 + skc,    &Asl[buf][t*8]);
        gload_lds16(A + (size_t)(m0+64+srow)*KDIM + k0 + skc, &Asl[buf][2048 + t*8]);
        gload_lds16(B + (size_t)br0*KDIM + k0 + skc,          &Bsl[buf][t*8]);
        gload_lds16(B + (size_t)br1*KDIM + k0 + skc,          &Bsl[buf][2048 + t*8]);
    };

    auto compute = [&](int cur){
        bf16x8 af[4], bfr[4];
        #pragma unroll
        for (int m=0;m<4;m++) af[m]  = *(const bf16x8*)&Asl[cur][(wr*64+m*16+lr16)*32 + kb*8];
        #pragma unroll
        for (int n=0;n<4;n++) bfr[n] = *(const bf16x8*)&Bsl[cur][(wc*64+n*16+lr16)*32 + kb*8];
        __builtin_amdgcn_s_setprio(1);
        #pragma unroll
        for (int m=0;m<4;m++){
            #pragma unroll
            for (int n=0;n<4;n++)
                acc[m][n] = __builtin_amdgcn_mfma_f32_16x16x32_bf16(af[m], bfr[n], acc[m][n], 0, 0, 0);
        }
        __builtin_amdgcn_s_setprio(0);
    };

    stage(0, 0);
    __syncthreads();
    int cur = 0;

    for (int k0=32; k0<KDIM; k0+=32){
        stage(cur^1, k0);
        compute(cur);
        __syncthreads();
        cur ^= 1;
    }
    compute(cur);

    #pragma unroll
    for (int m=0;m<4;m++){
        int rbase = m0 + wr*64 + m*16 + (l>>4)*4;
        #pragma unroll
        for (int n=0;n<4;n++){
            int gcol = n0 + wc*64 + n*16 + lr16;
            f32x4 v = acc[m][n];
            #pragma unroll
            for (int q=0;q<4;q++){
                int row = rbase + q;
                if (EPI == 0) {
                    outf[(size_t)row*DMODEL + gcol] = v[q];
                } else {
                    if (gcol < DINNER) {
                        z[(size_t)row*DINNER + gcol] = f2bf(v[q]);
                    } else if (gcol < DINNER + CONVDIM) {
                        xbc[(size_t)row*CONVDIM + (gcol - DINNER)] = f2bf(v[q]);
                    } else if (gcol < DINPROJ) {
                        int hh = gcol - (DINNER + CONVDIM);
                        float x = v[q] + dt_bias[hh];
                        float sp = (x > 15.f) ? x : log1pf(__expf(x));
                        int bb = row >> 11, ll = row & (L_N-1);
                        dtp[((size_t)bb*NHEADS + hh)*L_N + ll] = sp;
                    }
                }
            }
        }
    }
}

// ---------------------------------------------------------------------------
// K2: causal depthwise conv1d (width 4) + bias + SiLU — bf16x8 vectorized
// ---------------------------------------------------------------------------
__global__ __launch_bounds__(256) void conv_silu(
    const __hip_bfloat16* __restrict__ xraw,
    const float* __restrict__ cw, const float* __restrict__ cb,
    __hip_bfloat16* __restrict__ xout)
{
    int idx = blockIdx.x*256 + threadIdx.x;       // BL * (CONVDIM/8)
    int c8 = (idx % (CONVDIM/8))*8;
    int ml = idx / (CONVDIM/8);
    int b  = ml >> 11, l = ml & (L_N-1);
    const ushort_t* xr = (const ushort_t*)xraw;
    float acc[8];
    #pragma unroll
    for (int e=0;e<8;e++) acc[e] = cb[c8+e];
    #pragma unroll
    for (int k=0;k<DCONV;k++){
        int li = l - (DCONV-1) + k;
        if (li >= 0){
            bf16x8 v = *(const bf16x8*)&xr[((size_t)b*L_N + li)*CONVDIM + c8];
            #pragma unroll
            for (int e=0;e<8;e++)
                acc[e] += cw[(c8+e)*DCONV + k] * bfbits2f(((const ushort_t*)&v)[e]);
        }
    }
    ushort_t o[8];
    #pragma unroll
    for (int e=0;e<8;e++){
        float s = acc[e] / (1.f + __expf(-acc[e]));
        o[e] = f2bf(s);
    }
    *(uint4*)((ushort_t*)xout + (size_t)idx*8) = *(const uint4*)o;
}

// ---------------------------------------------------------------------------
// K3: dA = dt*A; inclusive cumsum within each chunk  (block per (b,h,c))
// ---------------------------------------------------------------------------
__global__ __launch_bounds__(256) void dt_cumsum(
    const float* __restrict__ dtp, const float* __restrict__ A_log,
    float* __restrict__ dAcs)
{
    int blk = blockIdx.x;
    int c  = blk % NCHUNK;
    int bh = blk / NCHUNK;
    int h  = bh & (NHEADS-1);
    int t  = threadIdx.x;
    float A = -__expf(A_log[h]);
    __shared__ float sm[CHUNK];
    float v = dtp[(size_t)bh*L_N + c*CHUNK + t] * A;
    sm[t] = v;
    __syncthreads();
    for (int off=1; off<CHUNK; off<<=1){
        float add = (t >= off) ? sm[t-off] : 0.f;
        __syncthreads();
        sm[t] += add;
        __syncthreads();
    }
    dAcs[(size_t)bh*L_N + c*CHUNK + t] = sm[t];
}

// ---------------------------------------------------------------------------
// K4: S_T[bc][j][i] = sum_n B[j,n]*C[i,n]  (bf16), once per chunk (head-shared).
// Block per bc, 4 waves; wave w owns j-rows [w*64, w*64+64). Triangular chunks.
// ---------------------------------------------------------------------------
__global__ __launch_bounds__(256) void bc_scores_mfma(
    const __hip_bfloat16* __restrict__ xbc, ushort_t* __restrict__ S_T)
{
    __shared__ __align__(16) ushort_t Bs2[256*136];   // 68 KB
    __shared__ __align__(16) ushort_t Cs2[256*136];   // 68 KB
    int bc = blockIdx.x;
    int t = threadIdx.x;
    int l = t & 63, w = t >> 6;
    int l15 = l & 15, l4 = l >> 4;
    const ushort_t* xb = (const ushort_t*)xbc;
    const size_t rowbase = (size_t)bc*CHUNK*CONVDIM;

    #pragma unroll
    for (int ps=0; ps<16; ps++){
        int idx = ps*256 + t;
        int r = idx >> 4, ck = idx & 15;
        *(uint4*)&Bs2[r*136 + ck*8] =
            *(const uint4*)&xb[rowbase + (size_t)r*CONVDIM + DINNER + ck*8];
        *(uint4*)&Cs2[r*136 + ck*8] =
            *(const uint4*)&xb[rowbase + (size_t)r*CONVDIM + (DINNER+DSTATE) + ck*8];
    }
    __syncthreads();

    ushort_t* Sb = S_T + (size_t)bc*CHUNK*264;
    for (int if4 = w; if4 < 4; if4++){     // only chunks with some j<=i
        f32x4 acc[4][4];
        #pragma unroll
        for (int jf=0;jf<4;jf++){
            #pragma unroll
            for (int ir=0;ir<4;ir++) acc[jf][ir] = (f32x4){0.f,0.f,0.f,0.f};
        }
        #pragma unroll
        for (int k=0;k<4;k++){
            bf16x8 af[4], bfC[4];
            #pragma unroll
            for (int jf=0;jf<4;jf++)
                af[jf] = *(const bf16x8*)&Bs2[(w*64 + jf*16 + l15)*136 + k*32 + l4*8];
            #pragma unroll
            for (int ir=0;ir<4;ir++)
                bfC[ir] = *(const bf16x8*)&Cs2[(if4*64 + ir*16 + l15)*136 + k*32 + l4*8];
            #pragma unroll
            for (int jf=0;jf<4;jf++){
                #pragma unroll
                for (int ir=0;ir<4;ir++)
                    acc[jf][ir] = __builtin_amdgcn_mfma_f32_16x16x32_bf16(af[jf], bfC[ir], acc[jf][ir], 0, 0, 0);
            }
        }
        #pragma unroll
        for (int jf=0;jf<4;jf++){
            #pragma unroll
            for (int ir=0;ir<4;ir++){
                #pragma unroll
                for (int q=0;q<4;q++){
                    int j = w*64 + jf*16 + l4*4 + q;
                    int i = if4*64 + ir*16 + l15;
                    Sb[(size_t)j*264 + i] = f2bf(acc[jf][ir][q]);
                }
            }
        }
    }
}

// ---------------------------------------------------------------------------
// K6: states[p][n] = sum_j (coef_j*x[j,p]) * B[j,n]  via MFMA.
// ---------------------------------------------------------------------------
__device__ __forceinline__ int swz264(int row, int col){
    return row*264 + (col ^ (((row>>3)&7)<<3));
}

__global__ __launch_bounds__(256) void ssd_states_mfma(
    const __hip_bfloat16* __restrict__ xbc,
    const float* __restrict__ dtp, const float* __restrict__ dAcs,
    float* __restrict__ states)
{
    __shared__ __align__(16) ushort_t xdT[64*264];
    __shared__ __align__(16) ushort_t BT[128*264];
    __shared__ float coef_s[CHUNK];
    int bc = blockIdx.x, h = blockIdx.y;
    int b = bc >> 3, c = bc & 7;
    int t = threadIdx.x;
    int l = t & 63, w = t >> 6;
    int l15 = l & 15, l4 = l >> 4;
    const ushort_t* xb = (const ushort_t*)xbc;
    const size_t rowbase = (size_t)bc*CHUNK*CONVDIM;

    size_t dbase = ((size_t)b*NHEADS + h)*L_N + c*CHUNK;
    float last = dAcs[dbase + CHUNK-1];
    coef_s[t] = __expf(last - dAcs[dbase + t]) * dtp[dbase + t];
    __syncthreads();

    #pragma unroll
    for (int ps=0; ps<8; ps++){
        int idx = ps*256 + t;
        int j = idx >> 3, p0 = (idx & 7)*8;
        float cj = coef_s[j];
        bf16x8 v = *(const bf16x8*)&xb[rowbase + (size_t)j*CONVDIM + h*HEADDIM + p0];
        #pragma unroll
        for (int e=0;e<8;e++)
            xdT[swz264(p0+e, j)] = f2bf(cj * bfbits2f(((const ushort_t*)&v)[e]));
    }
    #pragma unroll
    for (int ps=0; ps<16; ps++){
        int idx = ps*256 + t;
        int j = idx >> 4, n0 = (idx & 15)*8;
        bf16x8 v = *(const bf16x8*)&xb[rowbase + (size_t)j*CONVDIM + DINNER + n0];
        #pragma unroll
        for (int e=0;e<8;e++)
            BT[swz264(n0+e, j)] = ((const ushort_t*)&v)[e];
    }
    __syncthreads();

    f32x4 acc[4][2];
    #pragma unroll
    for (int pf=0;pf<4;pf++){
        #pragma unroll
        for (int nf=0;nf<2;nf++) acc[pf][nf] = (f32x4){0.f,0.f,0.f,0.f};
    }

    #pragma unroll
    for (int k=0;k<8;k++){
        bf16x8 af[4], bv[2];
        #pragma unroll
        for (int pf=0;pf<4;pf++)
            af[pf] = *(const bf16x8*)&xdT[swz264(pf*16 + l15, k*32 + l4*8)];
        #pragma unroll
        for (int nf=0;nf<2;nf++)
            bv[nf] = *(const bf16x8*)&BT[swz264(w*32 + nf*16 + l15, k*32 + l4*8)];
        #pragma unroll
        for (int pf=0;pf<4;pf++){
            #pragma unroll
            for (int nf=0;nf<2;nf++)
                acc[pf][nf] = __builtin_amdgcn_mfma_f32_16x16x32_bf16(af[pf], bv[nf], acc[pf][nf], 0, 0, 0);
        }
    }

    float* sb = states + (size_t)(bc*NHEADS + h)*HEADDIM*DSTATE;
    #pragma unroll
    for (int pf=0;pf<4;pf++){
        #pragma unroll
        for (int nf=0;nf<2;nf++){
            #pragma unroll
            for (int q=0;q<4;q++){
                int p = pf*16 + l4*4 + q;
                int n = w*32 + nf*16 + l15;
                sb[(size_t)p*DSTATE + n] = acc[pf][nf][q];
            }
        }
    }
}

// ---------------------------------------------------------------------------
// K7: inter-chunk scan (sequential over 8 chunks), in-place: states -> prev
// ---------------------------------------------------------------------------
__global__ __launch_bounds__(256) void scan_states(
    float* __restrict__ states, const float* __restrict__ dAcs)
{
    int idx = blockIdx.x*256 + threadIdx.x;
    int n  = idx & 127;
    int p  = (idx >> 7) & 63;
    int bh = idx >> 13;
    int b  = bh >> 5, h = bh & 31;
    float carry = 0.f;
    for (int c=0;c<NCHUNK;c++){
        size_t off = (((size_t)((b*NCHUNK + c)*NHEADS + h))*HEADDIM + p)*DSTATE + n;
        float s = states[off];
        states[off] = carry;
        float cd = __expf(dAcs[((size_t)b*NHEADS + h)*L_N + c*CHUNK + (CHUNK-1)]);
        carry = carry * cd + s;
    }
}

// ---------------------------------------------------------------------------
// K5: fused MFMA SSD: yh = exp(da_i)*(C@prev^T) + (W@x^T) + D*x
// W built from precomputed S_T (L2-hot). Barrier-free main loop.
// ---------------------------------------------------------------------------
__global__ __launch_bounds__(256, 1) void ssd_mfma(
    const __hip_bfloat16* __restrict__ xbc,
    const float* __restrict__ dtp, const float* __restrict__ dAcs,
    const float* __restrict__ states, const ushort_t* __restrict__ S_T,
    const float* __restrict__ D_param, float* __restrict__ yh)
{
    __shared__ __align__(16) ushort_t Cs[256*136];   // C tile (Y_off A-operand)
    __shared__ __align__(16) ushort_t Bs[64*136];    // prev (bf16)
    __shared__ __align__(16) ushort_t Ws[256*72];    // W panel (bf16, wave-private rows)
    __shared__ __align__(16) ushort_t xdT[64*264];   // x^T
    __shared__ float da_s[CHUNK];
    __shared__ float dt_s[CHUNK];

    int bc = blockIdx.x, h = blockIdx.y;
    int b = bc >> 3, c = bc & 7;
    int t = threadIdx.x;
    int l = t & 63, w = t >> 6;
    int l15 = l & 15, l4 = l >> 4;

    const ushort_t* xb = (const ushort_t*)xbc;
    const size_t rowbase = (size_t)bc*CHUNK*CONVDIM;

    da_s[t] = dAcs[((size_t)b*NHEADS + h)*L_N + c*CHUNK + t];
    dt_s[t] = dtp[((size_t)b*NHEADS + h)*L_N + c*CHUNK + t];

    #pragma unroll
    for (int ps=0; ps<16; ps++){
        int idx = ps*256 + t;
        int r = idx >> 4, ck = idx & 15;
        *(uint4*)&Cs[r*136 + ck*8] =
            *(const uint4*)&xb[rowbase + (size_t)r*CONVDIM + (DINNER+DSTATE) + ck*8];
    }
    #pragma unroll
    for (int ps=0; ps<8; ps++){
        int idx = ps*256 + t;
        int j = idx >> 3, p0 = (idx & 7)*8;
        bf16x8 v = *(const bf16x8*)&xb[rowbase + (size_t)j*CONVDIM + h*HEADDIM + p0];
        #pragma unroll
        for (int e=0;e<8;e++) xdT[(p0+e)*264 + j] = ((const ushort_t*)&v)[e];
    }
    const float* sbp = states + (size_t)(bc*NHEADS + h)*HEADDIM*DSTATE;
    #pragma unroll
    for (int ps=0; ps<8; ps++){
        int idx = ps*256 + t;
        int p = idx >> 5, n0 = (idx & 31)*4;
        float4 v = *(const float4*)&sbp[p*DSTATE + n0];
        ushort_t o[4] = { f2bf(v.x), f2bf(v.y), f2bf(v.z), f2bf(v.w) };
        *(uint2*)&Bs[p*136 + n0] = *(const uint2*)o;
    }
    __syncthreads();

    f32x4 yacc[4][4];
    #pragma unroll
    for (int m=0;m<4;m++){
        #pragma unroll
        for (int np=0;np<4;np++) yacc[m][np] = (f32x4){0.f,0.f,0.f,0.f};
    }

    // ---- Y_off = C @ prev^T
    #pragma unroll
    for (int k=0;k<4;k++){
        bf16x8 bfk[4];
        #pragma unroll
        for (int np=0;np<4;np++)
            bfk[np] = *(const bf16x8*)&Bs[(np*16 + l15)*136 + k*32 + l4*8];
        #pragma unroll
        for (int m=0;m<4;m++){
            int i0 = (m*4 + w)*16;
            bf16x8 af = *(const bf16x8*)&Cs[(i0 + l15)*136 + k*32 + l4*8];
            #pragma unroll
            for (int np=0;np<4;np++)
                yacc[m][np] = __builtin_amdgcn_mfma_f32_16x16x32_bf16(af, bfk[np], yacc[m][np], 0, 0, 0);
        }
    }
    #pragma unroll
    for (int m=0;m<4;m++){
        int i0 = (m*4 + w)*16;
        #pragma unroll
        for (int q=0;q<4;q++){
            float e = __expf(da_s[i0 + l4*4 + q]);
            #pragma unroll
            for (int np=0;np<4;np++) yacc[m][np][q] *= e;
        }
    }

    // ---- Y_diag panels (no barriers: Ws rows are wave-private, xdT read-only)
    const ushort_t* Sb = S_T + (size_t)bc*CHUNK*264;
    for (int jp=0; jp<4; jp++){
        bf16x8 bfx[4][2];
        #pragma unroll
        for (int np=0;np<4;np++){
            #pragma unroll
            for (int ks=0;ks<2;ks++)
                bfx[np][ks] = *(const bf16x8*)&xdT[(np*16 + l15)*264 + jp*64 + ks*32 + l4*8];
        }

        #pragma unroll
        for (int m=0;m<4;m++){
            int i0 = (m*4 + w)*16;
            int imax = i0 + 15;
            int kmaxY = (jp*64 <= imax ? 1 : 0) + (jp*64+32 <= imax ? 1 : 0);
            if (kmaxY == 0) continue;          // wave-uniform
            int nmax = 2*kmaxY;

            float dai[4];
            #pragma unroll
            for (int q=0;q<4;q++) dai[q] = da_s[i0 + l4*4 + q];
            #pragma unroll
            for (int n=0;n<4;n++){
                if (n < nmax){
                    int jcol = jp*64 + n*16 + l15;
                    float daj = da_s[jcol], dtj = dt_s[jcol];
                    ushort_t sv[4];
                    *(uint2*)sv = *(const uint2*)&Sb[(size_t)jcol*264 + i0 + l4*4];
                    #pragma unroll
                    for (int q=0;q<4;q++){
                        int i = i0 + l4*4 + q;
                        float wv = 0.f;
                        if (jcol <= i) wv = __expf(dai[q] - daj) * dtj * bfbits2f(sv[q]);
                        Ws[i*72 + n*16 + l15] = f2bf(wv);
                    }
                }
            }
            #pragma unroll
            for (int ks=0;ks<2;ks++){
                if (ks < kmaxY){
                    bf16x8 wfA = *(const bf16x8*)&Ws[(i0 + l15)*72 + ks*32 + l4*8];
                    #pragma unroll
                    for (int np=0;np<4;np++)
                        yacc[m][np] = __builtin_amdgcn_mfma_f32_16x16x32_bf16(wfA, bfx[np][ks], yacc[m][np], 0, 0, 0);
                }
            }
        }
    }

    // ---- epilogue: + D*x, store
    float Dh = D_param[h];
    #pragma unroll
    for (int m=0;m<4;m++){
        int i0 = (m*4 + w)*16;
        #pragma unroll
        for (int np=0;np<4;np++){
            int p = np*16 + l15;
            #pragma unroll
            for (int q=0;q<4;q++){
                int i = i0 + l4*4 + q;
                float xv = bfbits2f(xdT[p*264 + i]);
                yh[((size_t)bc*CHUNK + i)*DINNER + h*HEADDIM + p] = yacc[m][np][q] + Dh*xv;
            }
        }
    }
}

// ---------------------------------------------------------------------------
// K9: g = yh * silu(z); RMSNorm(g)*norm_w  -> bf16 g  (block per token row)
// ---------------------------------------------------------------------------
__global__ __launch_bounds__(256) void gate_norm(
    const float* __restrict__ yh, const __hip_bfloat16* __restrict__ z,
    const float* __restrict__ norm_w, __hip_bfloat16* __restrict__ g)
{
    int row = blockIdx.x;
    int t = threadIdx.x;
    const float* yr = yh + (size_t)row*DINNER;
    const ushort_t* zr = (const ushort_t*)z + (size_t)row*DINNER;
    float v[8];
    float ss = 0.f;
    #pragma unroll
    for (int r=0;r<8;r++){
        int d = r*256 + t;
        float zv = bfbits2f(zr[d]);
        float gv = yr[d] * (zv / (1.f + __expf(-zv)));
        v[r] = gv; ss += gv*gv;
    }
    #pragma unroll
    for (int off=32; off>=1; off>>=1) ss += __shfl_xor(ss, off);
    __shared__ float red[4];
    if ((t & 63) == 0) red[t >> 6] = ss;
    __syncthreads();
    float tot = red[0]+red[1]+red[2]+red[3];
    float scale = rsqrtf(tot * (1.f/DINNER) + 1e-5f);
    __hip_bfloat16* gr = g + (size_t)row*DINNER;
    #pragma unroll
    for (int r=0;r<8;r++){
        int d = r*256 + t;
        gr[d] = __float2bfloat16(v[r]*scale*norm_w[d]);
    }
}

// ---------------------------------------------------------------------------
extern "C" void kernel_launch(void* const* d_in, const int* in_sizes, int n_in,
                              void* d_out, int out_size, void* d_ws, size_t ws_size,
                              hipStream_t stream)
{
    const float* u       = (const float*)d_in[0];
    const float* W_in    = (const float*)d_in[1];
    const float* conv_w  = (const float*)d_in[2];
    const float* conv_b  = (const float*)d_in[3];
    const float* dt_bias = (const float*)d_in[4];
    const float* A_log   = (const float*)d_in[5];
    const float* D_param = (const float*)d_in[6];
    const float* norm_w  = (const float*)d_in[7];
    const float* W_out   = (const float*)d_in[8];
    float* out = (float*)d_out;

    char* p = (char*)d_ws;
    auto take = [&](size_t n){ char* r = p; p += (n + 255) & ~(size_t)255; return r; };

    __hip_bfloat16* z       = (__hip_bfloat16*)take((size_t)BL*DINNER*2);
    __hip_bfloat16* xbc_raw = (__hip_bfloat16*)take((size_t)BL*CONVDIM*2);
    __hip_bfloat16* xbc     = (__hip_bfloat16*)take((size_t)BL*CONVDIM*2);
    float* dtp     = (float*)take((size_t)BL*NHEADS*4);
    float* dAcs    = (float*)take((size_t)BL*NHEADS*4);
    float* states  = (float*)take((size_t)B_N*NCHUNK*NHEADS*HEADDIM*DSTATE*4);
    float* yh      = (float*)take((size_t)BL*DINNER*4);
    ushort_t* S_T  = (ushort_t*)take((size_t)B_N*NCHUNK*CHUNK*264*2);
    ushort_t* u_bf  = (ushort_t*)take((size_t)BL*DMODEL*2);
    ushort_t* Wi_bf = (ushort_t*)take((size_t)DINPROJ*DMODEL*2);
    ushort_t* Wo_bf = (ushort_t*)take((size_t)DMODEL*DINNER*2);
    __hip_bfloat16* g = z;   // alias: z dead after gate_norm's elementwise read

    cvt_bf16<<<dim3((BL*DMODEL/8 + 255)/256), 256, 0, stream>>>(u, u_bf, BL*DMODEL/8);
    cvt_bf16<<<dim3((DINPROJ*DMODEL/8 + 255)/256), 256, 0, stream>>>(W_in, Wi_bf, DINPROJ*DMODEL/8);
    cvt_bf16<<<dim3((DMODEL*DINNER/8 + 255)/256), 256, 0, stream>>>(W_out, Wo_bf, DMODEL*DINNER/8);

    // in-proj: z + xBC + dt (N = 4480 = 35 * 128, cols >=4384 dropped)
    gemm_bt_mfma<DMODEL,35,1><<<dim3(64*35), 256, 0, stream>>>(
        u_bf, Wi_bf, nullptr, (ushort_t*)z, (ushort_t*)xbc_raw, dt_bias, dtp);

    conv_silu<<<dim3(BL*(CONVDIM/8)/256), 256, 0, stream>>>(xbc_raw, conv_w, conv_b, xbc);
    dt_cumsum<<<dim3(B_N*NHEADS*NCHUNK), 256, 0, stream>>>(dtp, A_log, dAcs);
    bc_scores_mfma<<<dim3(B_N*NCHUNK), 256, 0, stream>>>(xbc, S_T);
    ssd_states_mfma<<<dim3(B_N*NCHUNK, NHEADS), 256, 0, stream>>>(xbc, dtp, dAcs, states);
    scan_states<<<dim3((B_N*NHEADS*HEADDIM*DSTATE)/256), 256, 0, stream>>>(states, dAcs);
    ssd_mfma<<<dim3(B_N*NCHUNK, NHEADS), 256, 0, stream>>>(xbc, dtp, dAcs, states, S_T, D_param, yh);
    gate_norm<<<dim3(BL), 256, 0, stream>>>(yh, z, norm_w, g);

    // out-proj
    gemm_bt_mfma<DINNER,8,0><<<dim3(64*8), 256, 0, stream>>>(
        (const ushort_t*)g, Wo_bf, out, nullptr, nullptr, nullptr, nullptr);
}

// Round 10
// 399.870 us; speedup vs baseline: 1.3606x; 1.2593x over previous
//
#include <hip/hip_runtime.h>
#include <hip/hip_bf16.h>
#include <math.h>

#define B_N     4
#define L_N     2048
#define DMODEL  1024
#define DSTATE  128
#define DCONV   4
#define HEADDIM 64
#define CHUNK   256
#define DINNER  2048
#define NHEADS  32
#define CONVDIM 2304
#define DINPROJ 4384
#define NCHUNK  8
#define BL      (B_N*L_N)

typedef unsigned short ushort_t;
typedef unsigned int   uint_t;

typedef __attribute__((ext_vector_type(8))) short bf16x8;
typedef __attribute__((ext_vector_type(4))) float f32x4;

__device__ __forceinline__ float bfbits2f(ushort_t u){
    union { uint_t i; float f; } v; v.i = ((uint_t)u) << 16; return v.f;
}
__device__ __forceinline__ ushort_t f2bf(float f){
    union { float f; uint_t i; } v; v.f = f;
    uint_t r = v.i + 0x7FFF + ((v.i >> 16) & 1);
    return (ushort_t)(r >> 16);
}
__device__ __forceinline__ void gload_lds16(const void* g, void* l){
    __builtin_amdgcn_global_load_lds(
        (const __attribute__((address_space(1))) unsigned int*)g,
        (__attribute__((address_space(3))) unsigned int*)l, 16, 0, 0);
}

// ---------------------------------------------------------------------------
// K0: f32 -> bf16 convert (8 elems/thread)
// ---------------------------------------------------------------------------
__global__ __launch_bounds__(256) void cvt_bf16(
    const float* __restrict__ in, ushort_t* __restrict__ out, int n8)
{
    int i = blockIdx.x*256 + threadIdx.x;
    if (i >= n8) return;
    const float4* p = (const float4*)(in + (size_t)i*8);
    float4 a = p[0], b = p[1];
    ushort_t o[8] = { f2bf(a.x), f2bf(a.y), f2bf(a.z), f2bf(a.w),
                      f2bf(b.x), f2bf(b.y), f2bf(b.z), f2bf(b.w) };
    *(uint4*)(out + (size_t)i*8) = *(const uint4*)o;
}

// ---------------------------------------------------------------------------
// K0b: transpose conv weights: wT[k][c] = cw[c][k]  (4 x 2304 f32)
// ---------------------------------------------------------------------------
__global__ __launch_bounds__(256) void cvt_wT(
    const float* __restrict__ cw, float* __restrict__ wT)
{
    int c = blockIdx.x*256 + threadIdx.x;
    if (c >= CONVDIM) return;
    float4 v = *(const float4*)&cw[c*DCONV];
    wT[0*CONVDIM + c] = v.x;
    wT[1*CONVDIM + c] = v.y;
    wT[2*CONVDIM + c] = v.z;
    wT[3*CONVDIM + c] = v.w;
}

// ---------------------------------------------------------------------------
// K1: bf16 MFMA GEMM, C = A @ B^T. 128x128 tile, BK=32, 4 waves.
// 2-phase double-buffered LDS + XCD-aware bijective swizzle. (R7 config)
// ---------------------------------------------------------------------------
template<int KDIM, int NTILES, int EPI>
__global__ __launch_bounds__(256) void gemm_bt_mfma(
    const ushort_t* __restrict__ A, const ushort_t* __restrict__ B,
    float* __restrict__ outf, ushort_t* __restrict__ z, ushort_t* __restrict__ xbc,
    const float* __restrict__ dt_bias, float* __restrict__ dtp)
{
    __shared__ __align__(16) ushort_t Asl[2][128*32];
    __shared__ __align__(16) ushort_t Bsl[2][128*32];

    int nwg = gridDim.x;
    int cpx = nwg >> 3;
    int lin = blockIdx.x;
    int work = (lin & 7)*cpx + (lin >> 3);
    int mtile = work / NTILES, ntile = work % NTILES;
    int m0 = mtile*128, n0 = ntile*128;

    int t = threadIdx.x;
    int l = t & 63, w = t >> 6;
    int wr = w >> 1, wc = w & 1;
    int lr16 = l & 15, kb = l >> 4;
    int srow = t >> 2, skc = (t & 3)*8;

    f32x4 acc[4][4];
    #pragma unroll
    for (int m=0;m<4;m++){
        #pragma unroll
        for (int n=0;n<4;n++) acc[m][n] = (f32x4){0.f,0.f,0.f,0.f};
    }

    int br0 = n0 + srow, br1 = n0 + 64 + srow;
    if (EPI == 1){
        br0 = (br0 < DINPROJ) ? br0 : (DINPROJ-1);
        br1 = (br1 < DINPROJ) ? br1 : (DINPROJ-1);
    }

    auto stage = [&](int buf, int k0){
        gload_lds16(A + (size_t)(m0+srow)*KDIM + k0 + skc,    &Asl[buf][t*8]);
        gload_lds16(A + (size_t)(m0+64+srow)*KDIM + k0 + skc, &Asl[buf][2048 + t*8]);
        gload_lds16(B + (size_t)br0*KDIM + k0 + skc,          &Bsl[buf][t*8]);
        gload_lds16(B + (size_t)br1*KDIM + k0 + skc,          &Bsl[buf][2048 + t*8]);
    };

    auto compute = [&](int cur){
        bf16x8 af[4], bfr[4];
        #pragma unroll
        for (int m=0;m<4;m++) af[m]  = *(const bf16x8*)&Asl[cur][(wr*64+m*16+lr16)*32 + kb*8];
        #pragma unroll
        for (int n=0;n<4;n++) bfr[n] = *(const bf16x8*)&Bsl[cur][(wc*64+n*16+lr16)*32 + kb*8];
        __builtin_amdgcn_s_setprio(1);
        #pragma unroll
        for (int m=0;m<4;m++){
            #pragma unroll
            for (int n=0;n<4;n++)
                acc[m][n] = __builtin_amdgcn_mfma_f32_16x16x32_bf16(af[m], bfr[n], acc[m][n], 0, 0, 0);
        }
        __builtin_amdgcn_s_setprio(0);
    };

    stage(0, 0);
    __syncthreads();
    int cur = 0;

    for (int k0=32; k0<KDIM; k0+=32){
        stage(cur^1, k0);
        compute(cur);
        __syncthreads();
        cur ^= 1;
    }
    compute(cur);

    #pragma unroll
    for (int m=0;m<4;m++){
        int rbase = m0 + wr*64 + m*16 + (l>>4)*4;
        #pragma unroll
        for (int n=0;n<4;n++){
            int gcol = n0 + wc*64 + n*16 + lr16;
            f32x4 v = acc[m][n];
            #pragma unroll
            for (int q=0;q<4;q++){
                int row = rbase + q;
                if (EPI == 0) {
                    outf[(size_t)row*DMODEL + gcol] = v[q];
                } else {
                    if (gcol < DINNER) {
                        z[(size_t)row*DINNER + gcol] = f2bf(v[q]);
                    } else if (gcol < DINNER + CONVDIM) {
                        xbc[(size_t)row*CONVDIM + (gcol - DINNER)] = f2bf(v[q]);
                    } else if (gcol < DINPROJ) {
                        int hh = gcol - (DINNER + CONVDIM);
                        float x = v[q] + dt_bias[hh];
                        float sp = (x > 15.f) ? x : log1pf(__expf(x));
                        int bb = row >> 11, ll = row & (L_N-1);
                        dtp[((size_t)bb*NHEADS + hh)*L_N + ll] = sp;
                    }
                }
            }
        }
    }
}

// ---------------------------------------------------------------------------
// K2: causal depthwise conv1d (width 4) + bias + SiLU — bf16x8 vectorized,
// transposed weights wT[k][c] (32B inter-lane stride, L1-hot)
// ---------------------------------------------------------------------------
__global__ __launch_bounds__(256) void conv_silu(
    const __hip_bfloat16* __restrict__ xraw,
    const float* __restrict__ wT, const float* __restrict__ cb,
    __hip_bfloat16* __restrict__ xout)
{
    int idx = blockIdx.x*256 + threadIdx.x;       // BL * (CONVDIM/8)
    int c8 = (idx % (CONVDIM/8))*8;
    int ml = idx / (CONVDIM/8);
    int b  = ml >> 11, l = ml & (L_N-1);
    const ushort_t* xr = (const ushort_t*)xraw;
    float acc[8];
    {
        float4 b0 = *(const float4*)&cb[c8];
        float4 b1 = *(const float4*)&cb[c8+4];
        acc[0]=b0.x; acc[1]=b0.y; acc[2]=b0.z; acc[3]=b0.w;
        acc[4]=b1.x; acc[5]=b1.y; acc[6]=b1.z; acc[7]=b1.w;
    }
    #pragma unroll
    for (int k=0;k<DCONV;k++){
        int li = l - (DCONV-1) + k;
        if (li >= 0){
            bf16x8 v = *(const bf16x8*)&xr[((size_t)b*L_N + li)*CONVDIM + c8];
            float4 w0 = *(const float4*)&wT[k*CONVDIM + c8];
            float4 w1 = *(const float4*)&wT[k*CONVDIM + c8 + 4];
            float wv[8] = {w0.x,w0.y,w0.z,w0.w,w1.x,w1.y,w1.z,w1.w};
            #pragma unroll
            for (int e=0;e<8;e++)
                acc[e] += wv[e] * bfbits2f(((const ushort_t*)&v)[e]);
        }
    }
    ushort_t o[8];
    #pragma unroll
    for (int e=0;e<8;e++){
        float s = acc[e] / (1.f + __expf(-acc[e]));
        o[e] = f2bf(s);
    }
    *(uint4*)((ushort_t*)xout + (size_t)idx*8) = *(const uint4*)o;
}

// ---------------------------------------------------------------------------
// K3: dA = dt*A; inclusive cumsum within each chunk  (block per (b,h,c))
// ---------------------------------------------------------------------------
__global__ __launch_bounds__(256) void dt_cumsum(
    const float* __restrict__ dtp, const float* __restrict__ A_log,
    float* __restrict__ dAcs)
{
    int blk = blockIdx.x;
    int c  = blk % NCHUNK;
    int bh = blk / NCHUNK;
    int h  = bh & (NHEADS-1);
    int t  = threadIdx.x;
    float A = -__expf(A_log[h]);
    __shared__ float sm[CHUNK];
    float v = dtp[(size_t)bh*L_N + c*CHUNK + t] * A;
    sm[t] = v;
    __syncthreads();
    for (int off=1; off<CHUNK; off<<=1){
        float add = (t >= off) ? sm[t-off] : 0.f;
        __syncthreads();
        sm[t] += add;
        __syncthreads();
    }
    dAcs[(size_t)bh*L_N + c*CHUNK + t] = sm[t];
}

// ---------------------------------------------------------------------------
// K4: S_T[bc][j][i] = sum_n B[j,n]*C[i,n]  (bf16), once per chunk (head-shared).
// ---------------------------------------------------------------------------
__global__ __launch_bounds__(256) void bc_scores_mfma(
    const __hip_bfloat16* __restrict__ xbc, ushort_t* __restrict__ S_T)
{
    __shared__ __align__(16) ushort_t Bs2[256*136];   // 68 KB
    __shared__ __align__(16) ushort_t Cs2[256*136];   // 68 KB
    int bc = blockIdx.x;
    int t = threadIdx.x;
    int l = t & 63, w = t >> 6;
    int l15 = l & 15, l4 = l >> 4;
    const ushort_t* xb = (const ushort_t*)xbc;
    const size_t rowbase = (size_t)bc*CHUNK*CONVDIM;

    #pragma unroll
    for (int ps=0; ps<16; ps++){
        int idx = ps*256 + t;
        int r = idx >> 4, ck = idx & 15;
        *(uint4*)&Bs2[r*136 + ck*8] =
            *(const uint4*)&xb[rowbase + (size_t)r*CONVDIM + DINNER + ck*8];
        *(uint4*)&Cs2[r*136 + ck*8] =
            *(const uint4*)&xb[rowbase + (size_t)r*CONVDIM + (DINNER+DSTATE) + ck*8];
    }
    __syncthreads();

    ushort_t* Sb = S_T + (size_t)bc*CHUNK*264;
    for (int if4 = w; if4 < 4; if4++){
        f32x4 acc[4][4];
        #pragma unroll
        for (int jf=0;jf<4;jf++){
            #pragma unroll
            for (int ir=0;ir<4;ir++) acc[jf][ir] = (f32x4){0.f,0.f,0.f,0.f};
        }
        #pragma unroll
        for (int k=0;k<4;k++){
            bf16x8 af[4], bfC[4];
            #pragma unroll
            for (int jf=0;jf<4;jf++)
                af[jf] = *(const bf16x8*)&Bs2[(w*64 + jf*16 + l15)*136 + k*32 + l4*8];
            #pragma unroll
            for (int ir=0;ir<4;ir++)
                bfC[ir] = *(const bf16x8*)&Cs2[(if4*64 + ir*16 + l15)*136 + k*32 + l4*8];
            #pragma unroll
            for (int jf=0;jf<4;jf++){
                #pragma unroll
                for (int ir=0;ir<4;ir++)
                    acc[jf][ir] = __builtin_amdgcn_mfma_f32_16x16x32_bf16(af[jf], bfC[ir], acc[jf][ir], 0, 0, 0);
            }
        }
        #pragma unroll
        for (int jf=0;jf<4;jf++){
            #pragma unroll
            for (int ir=0;ir<4;ir++){
                #pragma unroll
                for (int q=0;q<4;q++){
                    int j = w*64 + jf*16 + l4*4 + q;
                    int i = if4*64 + ir*16 + l15;
                    Sb[(size_t)j*264 + i] = f2bf(acc[jf][ir][q]);
                }
            }
        }
    }
}

// ---------------------------------------------------------------------------
// K6: states[p][n] = sum_j (coef_j*x[j,p]) * B[j,n]  via MFMA.
// ---------------------------------------------------------------------------
__device__ __forceinline__ int swz264(int row, int col){
    return row*264 + (col ^ (((row>>3)&7)<<3));
}

__global__ __launch_bounds__(256) void ssd_states_mfma(
    const __hip_bfloat16* __restrict__ xbc,
    const float* __restrict__ dtp, const float* __restrict__ dAcs,
    float* __restrict__ states)
{
    __shared__ __align__(16) ushort_t xdT[64*264];
    __shared__ __align__(16) ushort_t BT[128*264];
    __shared__ float coef_s[CHUNK];
    int bc = blockIdx.x, h = blockIdx.y;
    int b = bc >> 3, c = bc & 7;
    int t = threadIdx.x;
    int l = t & 63, w = t >> 6;
    int l15 = l & 15, l4 = l >> 4;
    const ushort_t* xb = (const ushort_t*)xbc;
    const size_t rowbase = (size_t)bc*CHUNK*CONVDIM;

    size_t dbase = ((size_t)b*NHEADS + h)*L_N + c*CHUNK;
    float last = dAcs[dbase + CHUNK-1];
    coef_s[t] = __expf(last - dAcs[dbase + t]) * dtp[dbase + t];
    __syncthreads();

    #pragma unroll
    for (int ps=0; ps<8; ps++){
        int idx = ps*256 + t;
        int j = idx >> 3, p0 = (idx & 7)*8;
        float cj = coef_s[j];
        bf16x8 v = *(const bf16x8*)&xb[rowbase + (size_t)j*CONVDIM + h*HEADDIM + p0];
        #pragma unroll
        for (int e=0;e<8;e++)
            xdT[swz264(p0+e, j)] = f2bf(cj * bfbits2f(((const ushort_t*)&v)[e]));
    }
    #pragma unroll
    for (int ps=0; ps<16; ps++){
        int idx = ps*256 + t;
        int j = idx >> 4, n0 = (idx & 15)*8;
        bf16x8 v = *(const bf16x8*)&xb[rowbase + (size_t)j*CONVDIM + DINNER + n0];
        #pragma unroll
        for (int e=0;e<8;e++)
            BT[swz264(n0+e, j)] = ((const ushort_t*)&v)[e];
    }
    __syncthreads();

    f32x4 acc[4][2];
    #pragma unroll
    for (int pf=0;pf<4;pf++){
        #pragma unroll
        for (int nf=0;nf<2;nf++) acc[pf][nf] = (f32x4){0.f,0.f,0.f,0.f};
    }

    #pragma unroll
    for (int k=0;k<8;k++){
        bf16x8 af[4], bv[2];
        #pragma unroll
        for (int pf=0;pf<4;pf++)
            af[pf] = *(const bf16x8*)&xdT[swz264(pf*16 + l15, k*32 + l4*8)];
        #pragma unroll
        for (int nf=0;nf<2;nf++)
            bv[nf] = *(const bf16x8*)&BT[swz264(w*32 + nf*16 + l15, k*32 + l4*8)];
        #pragma unroll
        for (int pf=0;pf<4;pf++){
            #pragma unroll
            for (int nf=0;nf<2;nf++)
                acc[pf][nf] = __builtin_amdgcn_mfma_f32_16x16x32_bf16(af[pf], bv[nf], acc[pf][nf], 0, 0, 0);
        }
    }

    float* sb = states + (size_t)(bc*NHEADS + h)*HEADDIM*DSTATE;
    #pragma unroll
    for (int pf=0;pf<4;pf++){
        #pragma unroll
        for (int nf=0;nf<2;nf++){
            #pragma unroll
            for (int q=0;q<4;q++){
                int p = pf*16 + l4*4 + q;
                int n = w*32 + nf*16 + l15;
                sb[(size_t)p*DSTATE + n] = acc[pf][nf][q];
            }
        }
    }
}

// ---------------------------------------------------------------------------
// K7: inter-chunk scan (sequential over 8 chunks), in-place: states -> prev
// ---------------------------------------------------------------------------
__global__ __launch_bounds__(256) void scan_states(
    float* __restrict__ states, const float* __restrict__ dAcs)
{
    int idx = blockIdx.x*256 + threadIdx.x;
    int n  = idx & 127;
    int p  = (idx >> 7) & 63;
    int bh = idx >> 13;
    int b  = bh >> 5, h = bh & 31;
    float carry = 0.f;
    for (int c=0;c<NCHUNK;c++){
        size_t off = (((size_t)((b*NCHUNK + c)*NHEADS + h))*HEADDIM + p)*DSTATE + n;
        float s = states[off];
        states[off] = carry;
        float cd = __expf(dAcs[((size_t)b*NHEADS + h)*L_N + c*CHUNK + (CHUNK-1)]);
        carry = carry * cd + s;
    }
}

// ---------------------------------------------------------------------------
// K5: fused MFMA SSD: yh = exp(da_i)*(C@prev^T) + (W@x^T) + D*x
// ---------------------------------------------------------------------------
__global__ __launch_bounds__(256, 1) void ssd_mfma(
    const __hip_bfloat16* __restrict__ xbc,
    const float* __restrict__ dtp, const float* __restrict__ dAcs,
    const float* __restrict__ states, const ushort_t* __restrict__ S_T,
    const float* __restrict__ D_param, float* __restrict__ yh)
{
    __shared__ __align__(16) ushort_t Cs[256*136];
    __shared__ __align__(16) ushort_t Bs[64*136];
    __shared__ __align__(16) ushort_t Ws[256*72];
    __shared__ __align__(16) ushort_t xdT[64*264];
    __shared__ float da_s[CHUNK];
    __shared__ float dt_s[CHUNK];

    int bc = blockIdx.x, h = blockIdx.y;
    int b = bc >> 3, c = bc & 7;
    int t = threadIdx.x;
    int l = t & 63, w = t >> 6;
    int l15 = l & 15, l4 = l >> 4;

    const ushort_t* xb = (const ushort_t*)xbc;
    const size_t rowbase = (size_t)bc*CHUNK*CONVDIM;

    da_s[t] = dAcs[((size_t)b*NHEADS + h)*L_N + c*CHUNK + t];
    dt_s[t] = dtp[((size_t)b*NHEADS + h)*L_N + c*CHUNK + t];

    #pragma unroll
    for (int ps=0; ps<16; ps++){
        int idx = ps*256 + t;
        int r = idx >> 4, ck = idx & 15;
        *(uint4*)&Cs[r*136 + ck*8] =
            *(const uint4*)&xb[rowbase + (size_t)r*CONVDIM + (DINNER+DSTATE) + ck*8];
    }
    #pragma unroll
    for (int ps=0; ps<8; ps++){
        int idx = ps*256 + t;
        int j = idx >> 3, p0 = (idx & 7)*8;
        bf16x8 v = *(const bf16x8*)&xb[rowbase + (size_t)j*CONVDIM + h*HEADDIM + p0];
        #pragma unroll
        for (int e=0;e<8;e++) xdT[(p0+e)*264 + j] = ((const ushort_t*)&v)[e];
    }
    const float* sbp = states + (size_t)(bc*NHEADS + h)*HEADDIM*DSTATE;
    #pragma unroll
    for (int ps=0; ps<8; ps++){
        int idx = ps*256 + t;
        int p = idx >> 5, n0 = (idx & 31)*4;
        float4 v = *(const float4*)&sbp[p*DSTATE + n0];
        ushort_t o[4] = { f2bf(v.x), f2bf(v.y), f2bf(v.z), f2bf(v.w) };
        *(uint2*)&Bs[p*136 + n0] = *(const uint2*)o;
    }
    __syncthreads();

    f32x4 yacc[4][4];
    #pragma unroll
    for (int m=0;m<4;m++){
        #pragma unroll
        for (int np=0;np<4;np++) yacc[m][np] = (f32x4){0.f,0.f,0.f,0.f};
    }

    // ---- Y_off = C @ prev^T
    #pragma unroll
    for (int k=0;k<4;k++){
        bf16x8 bfk[4];
        #pragma unroll
        for (int np=0;np<4;np++)
            bfk[np] = *(const bf16x8*)&Bs[(np*16 + l15)*136 + k*32 + l4*8];
        #pragma unroll
        for (int m=0;m<4;m++){
            int i0 = (m*4 + w)*16;
            bf16x8 af = *(const bf16x8*)&Cs[(i0 + l15)*136 + k*32 + l4*8];
            #pragma unroll
            for (int np=0;np<4;np++)
                yacc[m][np] = __builtin_amdgcn_mfma_f32_16x16x32_bf16(af, bfk[np], yacc[m][np], 0, 0, 0);
        }
    }
    #pragma unroll
    for (int m=0;m<4;m++){
        int i0 = (m*4 + w)*16;
        #pragma unroll
        for (int q=0;q<4;q++){
            float e = __expf(da_s[i0 + l4*4 + q]);
            #pragma unroll
            for (int np=0;np<4;np++) yacc[m][np][q] *= e;
        }
    }

    // ---- Y_diag panels (no barriers: Ws rows are wave-private, xdT read-only)
    const ushort_t* Sb = S_T + (size_t)bc*CHUNK*264;
    for (int jp=0; jp<4; jp++){
        bf16x8 bfx[4][2];
        #pragma unroll
        for (int np=0;np<4;np++){
            #pragma unroll
            for (int ks=0;ks<2;ks++)
                bfx[np][ks] = *(const bf16x8*)&xdT[(np*16 + l15)*264 + jp*64 + ks*32 + l4*8];
        }

        #pragma unroll
        for (int m=0;m<4;m++){
            int i0 = (m*4 + w)*16;
            int imax = i0 + 15;
            int kmaxY = (jp*64 <= imax ? 1 : 0) + (jp*64+32 <= imax ? 1 : 0);
            if (kmaxY == 0) continue;
            int nmax = 2*kmaxY;

            float dai[4];
            #pragma unroll
            for (int q=0;q<4;q++) dai[q] = da_s[i0 + l4*4 + q];
            #pragma unroll
            for (int n=0;n<4;n++){
                if (n < nmax){
                    int jcol = jp*64 + n*16 + l15;
                    float daj = da_s[jcol], dtj = dt_s[jcol];
                    ushort_t sv[4];
                    *(uint2*)sv = *(const uint2*)&Sb[(size_t)jcol*264 + i0 + l4*4];
                    #pragma unroll
                    for (int q=0;q<4;q++){
                        int i = i0 + l4*4 + q;
                        float wv = 0.f;
                        if (jcol <= i) wv = __expf(dai[q] - daj) * dtj * bfbits2f(sv[q]);
                        Ws[i*72 + n*16 + l15] = f2bf(wv);
                    }
                }
            }
            #pragma unroll
            for (int ks=0;ks<2;ks++){
                if (ks < kmaxY){
                    bf16x8 wfA = *(const bf16x8*)&Ws[(i0 + l15)*72 + ks*32 + l4*8];
                    #pragma unroll
                    for (int np=0;np<4;np++)
                        yacc[m][np] = __builtin_amdgcn_mfma_f32_16x16x32_bf16(wfA, bfx[np][ks], yacc[m][np], 0, 0, 0);
                }
            }
        }
    }

    // ---- epilogue: + D*x, store
    float Dh = D_param[h];
    #pragma unroll
    for (int m=0;m<4;m++){
        int i0 = (m*4 + w)*16;
        #pragma unroll
        for (int np=0;np<4;np++){
            int p = np*16 + l15;
            #pragma unroll
            for (int q=0;q<4;q++){
                int i = i0 + l4*4 + q;
                float xv = bfbits2f(xdT[p*264 + i]);
                yh[((size_t)bc*CHUNK + i)*DINNER + h*HEADDIM + p] = yacc[m][np][q] + Dh*xv;
            }
        }
    }
}

// ---------------------------------------------------------------------------
// K9: g = yh * silu(z); RMSNorm(g)*norm_w  -> bf16 g  (block per token row)
// ---------------------------------------------------------------------------
__global__ __launch_bounds__(256) void gate_norm(
    const float* __restrict__ yh, const __hip_bfloat16* __restrict__ z,
    const float* __restrict__ norm_w, __hip_bfloat16* __restrict__ g)
{
    int row = blockIdx.x;
    int t = threadIdx.x;
    const float* yr = yh + (size_t)row*DINNER;
    const ushort_t* zr = (const ushort_t*)z + (size_t)row*DINNER;
    float v[8];
    float ss = 0.f;
    #pragma unroll
    for (int r=0;r<8;r++){
        int d = r*256 + t;
        float zv = bfbits2f(zr[d]);
        float gv = yr[d] * (zv / (1.f + __expf(-zv)));
        v[r] = gv; ss += gv*gv;
    }
    #pragma unroll
    for (int off=32; off>=1; off>>=1) ss += __shfl_xor(ss, off);
    __shared__ float red[4];
    if ((t & 63) == 0) red[t >> 6] = ss;
    __syncthreads();
    float tot = red[0]+red[1]+red[2]+red[3];
    float scale = rsqrtf(tot * (1.f/DINNER) + 1e-5f);
    __hip_bfloat16* gr = g + (size_t)row*DINNER;
    #pragma unroll
    for (int r=0;r<8;r++){
        int d = r*256 + t;
        gr[d] = __float2bfloat16(v[r]*scale*norm_w[d]);
    }
}

// ---------------------------------------------------------------------------
extern "C" void kernel_launch(void* const* d_in, const int* in_sizes, int n_in,
                              void* d_out, int out_size, void* d_ws, size_t ws_size,
                              hipStream_t stream)
{
    const float* u       = (const float*)d_in[0];
    const float* W_in    = (const float*)d_in[1];
    const float* conv_w  = (const float*)d_in[2];
    const float* conv_b  = (const float*)d_in[3];
    const float* dt_bias = (const float*)d_in[4];
    const float* A_log   = (const float*)d_in[5];
    const float* D_param = (const float*)d_in[6];
    const float* norm_w  = (const float*)d_in[7];
    const float* W_out   = (const float*)d_in[8];
    float* out = (float*)d_out;

    char* p = (char*)d_ws;
    auto take = [&](size_t n){ char* r = p; p += (n + 255) & ~(size_t)255; return r; };

    __hip_bfloat16* z       = (__hip_bfloat16*)take((size_t)BL*DINNER*2);
    __hip_bfloat16* xbc_raw = (__hip_bfloat16*)take((size_t)BL*CONVDIM*2);
    __hip_bfloat16* xbc     = (__hip_bfloat16*)take((size_t)BL*CONVDIM*2);
    float* dtp     = (float*)take((size_t)BL*NHEADS*4);
    float* dAcs    = (float*)take((size_t)BL*NHEADS*4);
    float* states  = (float*)take((size_t)B_N*NCHUNK*NHEADS*HEADDIM*DSTATE*4);
    float* yh      = (float*)take((size_t)BL*DINNER*4);
    ushort_t* S_T  = (ushort_t*)take((size_t)B_N*NCHUNK*CHUNK*264*2);
    ushort_t* u_bf  = (ushort_t*)take((size_t)BL*DMODEL*2);
    ushort_t* Wi_bf = (ushort_t*)take((size_t)DINPROJ*DMODEL*2);
    ushort_t* Wo_bf = (ushort_t*)take((size_t)DMODEL*DINNER*2);
    float* wT       = (float*)take((size_t)DCONV*CONVDIM*4);
    __hip_bfloat16* g = z;   // alias: z dead after gate_norm's elementwise read

    cvt_bf16<<<dim3((BL*DMODEL/8 + 255)/256), 256, 0, stream>>>(u, u_bf, BL*DMODEL/8);
    cvt_bf16<<<dim3((DINPROJ*DMODEL/8 + 255)/256), 256, 0, stream>>>(W_in, Wi_bf, DINPROJ*DMODEL/8);
    cvt_bf16<<<dim3((DMODEL*DINNER/8 + 255)/256), 256, 0, stream>>>(W_out, Wo_bf, DMODEL*DINNER/8);
    cvt_wT<<<dim3((CONVDIM+255)/256), 256, 0, stream>>>(conv_w, wT);

    // in-proj: z + xBC + dt (N = 4480 = 35 * 128, cols >=4384 dropped)
    gemm_bt_mfma<DMODEL,35,1><<<dim3(64*35), 256, 0, stream>>>(
        u_bf, Wi_bf, nullptr, (ushort_t*)z, (ushort_t*)xbc_raw, dt_bias, dtp);

    conv_silu<<<dim3(BL*(CONVDIM/8)/256), 256, 0, stream>>>(xbc_raw, wT, conv_b, xbc);
    dt_cumsum<<<dim3(B_N*NHEADS*NCHUNK), 256, 0, stream>>>(dtp, A_log, dAcs);
    bc_scores_mfma<<<dim3(B_N*NCHUNK), 256, 0, stream>>>(xbc, S_T);
    ssd_states_mfma<<<dim3(B_N*NCHUNK, NHEADS), 256, 0, stream>>>(xbc, dtp, dAcs, states);
    scan_states<<<dim3((B_N*NHEADS*HEADDIM*DSTATE)/256), 256, 0, stream>>>(states, dAcs);
    ssd_mfma<<<dim3(B_N*NCHUNK, NHEADS), 256, 0, stream>>>(xbc, dtp, dAcs, states, S_T, D_param, yh);
    gate_norm<<<dim3(BL), 256, 0, stream>>>(yh, z, norm_w, g);

    // out-proj
    gemm_bt_mfma<DINNER,8,0><<<dim3(64*8), 256, 0, stream>>>(
        (const ushort_t*)g, Wo_bf, out, nullptr, nullptr, nullptr, nullptr);
}

// Round 11
// 366.501 us; speedup vs baseline: 1.4844x; 1.0910x over previous
//
#include <hip/hip_runtime.h>
#include <hip/hip_bf16.h>
#include <math.h>

#define B_N     4
#define L_N     2048
#define DMODEL  1024
#define DSTATE  128
#define DCONV   4
#define HEADDIM 64
#define CHUNK   256
#define DINNER  2048
#define NHEADS  32
#define CONVDIM 2304
#define DINPROJ 4384
#define NCHUNK  8
#define BL      (B_N*L_N)

typedef unsigned short ushort_t;
typedef unsigned int   uint_t;

typedef __attribute__((ext_vector_type(8))) short bf16x8;
typedef __attribute__((ext_vector_type(4))) float f32x4;

__device__ __forceinline__ float bfbits2f(ushort_t u){
    union { uint_t i; float f; } v; v.i = ((uint_t)u) << 16; return v.f;
}
__device__ __forceinline__ ushort_t f2bf(float f){
    union { float f; uint_t i; } v; v.f = f;
    uint_t r = v.i + 0x7FFF + ((v.i >> 16) & 1);
    return (ushort_t)(r >> 16);
}
__device__ __forceinline__ void gload_lds16(const void* g, void* l){
    __builtin_amdgcn_global_load_lds(
        (const __attribute__((address_space(1))) unsigned int*)g,
        (__attribute__((address_space(3))) unsigned int*)l, 16, 0, 0);
}

// ---------------------------------------------------------------------------
// K0: f32 -> bf16 convert (8 elems/thread)
// ---------------------------------------------------------------------------
__global__ __launch_bounds__(256) void cvt_bf16(
    const float* __restrict__ in, ushort_t* __restrict__ out, int n8)
{
    int i = blockIdx.x*256 + threadIdx.x;
    if (i >= n8) return;
    const float4* p = (const float4*)(in + (size_t)i*8);
    float4 a = p[0], b = p[1];
    ushort_t o[8] = { f2bf(a.x), f2bf(a.y), f2bf(a.z), f2bf(a.w),
                      f2bf(b.x), f2bf(b.y), f2bf(b.z), f2bf(b.w) };
    *(uint4*)(out + (size_t)i*8) = *(const uint4*)o;
}

// ---------------------------------------------------------------------------
// K0b: transpose conv weights: wT[k][c] = cw[c][k]  (4 x 2304 f32)
// ---------------------------------------------------------------------------
__global__ __launch_bounds__(256) void cvt_wT(
    const float* __restrict__ cw, float* __restrict__ wT)
{
    int c = blockIdx.x*256 + threadIdx.x;
    if (c >= CONVDIM) return;
    float4 v = *(const float4*)&cw[c*DCONV];
    wT[0*CONVDIM + c] = v.x;
    wT[1*CONVDIM + c] = v.y;
    wT[2*CONVDIM + c] = v.z;
    wT[3*CONVDIM + c] = v.w;
}

// ---------------------------------------------------------------------------
// K1: bf16 MFMA GEMM, C = A @ B^T. 128x128 tile, BK=32, 4 waves.
// 2-phase double-buffered LDS + XCD-aware bijective swizzle. (R7 config)
// ---------------------------------------------------------------------------
template<int KDIM, int NTILES, int EPI>
__global__ __launch_bounds__(256) void gemm_bt_mfma(
    const ushort_t* __restrict__ A, const ushort_t* __restrict__ B,
    float* __restrict__ outf, ushort_t* __restrict__ z, ushort_t* __restrict__ xbc,
    const float* __restrict__ dt_bias, float* __restrict__ dtp)
{
    __shared__ __align__(16) ushort_t Asl[2][128*32];
    __shared__ __align__(16) ushort_t Bsl[2][128*32];

    int nwg = gridDim.x;
    int cpx = nwg >> 3;
    int lin = blockIdx.x;
    int work = (lin & 7)*cpx + (lin >> 3);
    int mtile = work / NTILES, ntile = work % NTILES;
    int m0 = mtile*128, n0 = ntile*128;

    int t = threadIdx.x;
    int l = t & 63, w = t >> 6;
    int wr = w >> 1, wc = w & 1;
    int lr16 = l & 15, kb = l >> 4;
    int srow = t >> 2, skc = (t & 3)*8;

    f32x4 acc[4][4];
    #pragma unroll
    for (int m=0;m<4;m++){
        #pragma unroll
        for (int n=0;n<4;n++) acc[m][n] = (f32x4){0.f,0.f,0.f,0.f};
    }

    int br0 = n0 + srow, br1 = n0 + 64 + srow;
    if (EPI == 1){
        br0 = (br0 < DINPROJ) ? br0 : (DINPROJ-1);
        br1 = (br1 < DINPROJ) ? br1 : (DINPROJ-1);
    }

    auto stage = [&](int buf, int k0){
        gload_lds16(A + (size_t)(m0+srow)*KDIM + k0 + skc,    &Asl[buf][t*8]);
        gload_lds16(A + (size_t)(m0+64+srow)*KDIM + k0 + skc, &Asl[buf][2048 + t*8]);
        gload_lds16(B + (size_t)br0*KDIM + k0 + skc,          &Bsl[buf][t*8]);
        gload_lds16(B + (size_t)br1*KDIM + k0 + skc,          &Bsl[buf][2048 + t*8]);
    };

    auto compute = [&](int cur){
        bf16x8 af[4], bfr[4];
        #pragma unroll
        for (int m=0;m<4;m++) af[m]  = *(const bf16x8*)&Asl[cur][(wr*64+m*16+lr16)*32 + kb*8];
        #pragma unroll
        for (int n=0;n<4;n++) bfr[n] = *(const bf16x8*)&Bsl[cur][(wc*64+n*16+lr16)*32 + kb*8];
        __builtin_amdgcn_s_setprio(1);
        #pragma unroll
        for (int m=0;m<4;m++){
            #pragma unroll
            for (int n=0;n<4;n++)
                acc[m][n] = __builtin_amdgcn_mfma_f32_16x16x32_bf16(af[m], bfr[n], acc[m][n], 0, 0, 0);
        }
        __builtin_amdgcn_s_setprio(0);
    };

    stage(0, 0);
    __syncthreads();
    int cur = 0;

    for (int k0=32; k0<KDIM; k0+=32){
        stage(cur^1, k0);
        compute(cur);
        __syncthreads();
        cur ^= 1;
    }
    compute(cur);

    #pragma unroll
    for (int m=0;m<4;m++){
        int rbase = m0 + wr*64 + m*16 + (l>>4)*4;
        #pragma unroll
        for (int n=0;n<4;n++){
            int gcol = n0 + wc*64 + n*16 + lr16;
            f32x4 v = acc[m][n];
            #pragma unroll
            for (int q=0;q<4;q++){
                int row = rbase + q;
                if (EPI == 0) {
                    outf[(size_t)row*DMODEL + gcol] = v[q];
                } else {
                    if (gcol < DINNER) {
                        z[(size_t)row*DINNER + gcol] = f2bf(v[q]);
                    } else if (gcol < DINNER + CONVDIM) {
                        xbc[(size_t)row*CONVDIM + (gcol - DINNER)] = f2bf(v[q]);
                    } else if (gcol < DINPROJ) {
                        int hh = gcol - (DINNER + CONVDIM);
                        float x = v[q] + dt_bias[hh];
                        float sp = (x > 15.f) ? x : log1pf(__expf(x));
                        int bb = row >> 11, ll = row & (L_N-1);
                        dtp[((size_t)bb*NHEADS + hh)*L_N + ll] = sp;
                    }
                }
            }
        }
    }
}

// ---------------------------------------------------------------------------
// K2: causal depthwise conv1d (width 4) + bias + SiLU — bf16x8, wT[k][c]
// ---------------------------------------------------------------------------
__global__ __launch_bounds__(256) void conv_silu(
    const __hip_bfloat16* __restrict__ xraw,
    const float* __restrict__ wT, const float* __restrict__ cb,
    __hip_bfloat16* __restrict__ xout)
{
    int idx = blockIdx.x*256 + threadIdx.x;       // BL * (CONVDIM/8)
    int c8 = (idx % (CONVDIM/8))*8;
    int ml = idx / (CONVDIM/8);
    int b  = ml >> 11, l = ml & (L_N-1);
    const ushort_t* xr = (const ushort_t*)xraw;
    float acc[8];
    {
        float4 b0 = *(const float4*)&cb[c8];
        float4 b1 = *(const float4*)&cb[c8+4];
        acc[0]=b0.x; acc[1]=b0.y; acc[2]=b0.z; acc[3]=b0.w;
        acc[4]=b1.x; acc[5]=b1.y; acc[6]=b1.z; acc[7]=b1.w;
    }
    #pragma unroll
    for (int k=0;k<DCONV;k++){
        int li = l - (DCONV-1) + k;
        if (li >= 0){
            bf16x8 v = *(const bf16x8*)&xr[((size_t)b*L_N + li)*CONVDIM + c8];
            float4 w0 = *(const float4*)&wT[k*CONVDIM + c8];
            float4 w1 = *(const float4*)&wT[k*CONVDIM + c8 + 4];
            float wv[8] = {w0.x,w0.y,w0.z,w0.w,w1.x,w1.y,w1.z,w1.w};
            #pragma unroll
            for (int e=0;e<8;e++)
                acc[e] += wv[e] * bfbits2f(((const ushort_t*)&v)[e]);
        }
    }
    ushort_t o[8];
    #pragma unroll
    for (int e=0;e<8;e++){
        float s = acc[e] / (1.f + __expf(-acc[e]));
        o[e] = f2bf(s);
    }
    *(uint4*)((ushort_t*)xout + (size_t)idx*8) = *(const uint4*)o;
}

// ---------------------------------------------------------------------------
// K3: dA = dt*A; inclusive cumsum within each chunk  (block per (b,h,c))
// ---------------------------------------------------------------------------
__global__ __launch_bounds__(256) void dt_cumsum(
    const float* __restrict__ dtp, const float* __restrict__ A_log,
    float* __restrict__ dAcs)
{
    int blk = blockIdx.x;
    int c  = blk % NCHUNK;
    int bh = blk / NCHUNK;
    int h  = bh & (NHEADS-1);
    int t  = threadIdx.x;
    float A = -__expf(A_log[h]);
    __shared__ float sm[CHUNK];
    float v = dtp[(size_t)bh*L_N + c*CHUNK + t] * A;
    sm[t] = v;
    __syncthreads();
    for (int off=1; off<CHUNK; off<<=1){
        float add = (t >= off) ? sm[t-off] : 0.f;
        __syncthreads();
        sm[t] += add;
        __syncthreads();
    }
    dAcs[(size_t)bh*L_N + c*CHUNK + t] = sm[t];
}

// ---------------------------------------------------------------------------
// K4: S_T[bc][j][i] = sum_n B[j,n]*C[i,n]  (bf16), once per chunk (head-shared).
// ---------------------------------------------------------------------------
__global__ __launch_bounds__(256) void bc_scores_mfma(
    const __hip_bfloat16* __restrict__ xbc, ushort_t* __restrict__ S_T)
{
    __shared__ __align__(16) ushort_t Bs2[256*136];   // 68 KB
    __shared__ __align__(16) ushort_t Cs2[256*136];   // 68 KB
    int bc = blockIdx.x;
    int t = threadIdx.x;
    int l = t & 63, w = t >> 6;
    int l15 = l & 15, l4 = l >> 4;
    const ushort_t* xb = (const ushort_t*)xbc;
    const size_t rowbase = (size_t)bc*CHUNK*CONVDIM;

    #pragma unroll
    for (int ps=0; ps<16; ps++){
        int idx = ps*256 + t;
        int r = idx >> 4, ck = idx & 15;
        *(uint4*)&Bs2[r*136 + ck*8] =
            *(const uint4*)&xb[rowbase + (size_t)r*CONVDIM + DINNER + ck*8];
        *(uint4*)&Cs2[r*136 + ck*8] =
            *(const uint4*)&xb[rowbase + (size_t)r*CONVDIM + (DINNER+DSTATE) + ck*8];
    }
    __syncthreads();

    ushort_t* Sb = S_T + (size_t)bc*CHUNK*264;
    for (int if4 = w; if4 < 4; if4++){
        f32x4 acc[4][4];
        #pragma unroll
        for (int jf=0;jf<4;jf++){
            #pragma unroll
            for (int ir=0;ir<4;ir++) acc[jf][ir] = (f32x4){0.f,0.f,0.f,0.f};
        }
        #pragma unroll
        for (int k=0;k<4;k++){
            bf16x8 af[4], bfC[4];
            #pragma unroll
            for (int jf=0;jf<4;jf++)
                af[jf] = *(const bf16x8*)&Bs2[(w*64 + jf*16 + l15)*136 + k*32 + l4*8];
            #pragma unroll
            for (int ir=0;ir<4;ir++)
                bfC[ir] = *(const bf16x8*)&Cs2[(if4*64 + ir*16 + l15)*136 + k*32 + l4*8];
            #pragma unroll
            for (int jf=0;jf<4;jf++){
                #pragma unroll
                for (int ir=0;ir<4;ir++)
                    acc[jf][ir] = __builtin_amdgcn_mfma_f32_16x16x32_bf16(af[jf], bfC[ir], acc[jf][ir], 0, 0, 0);
            }
        }
        #pragma unroll
        for (int jf=0;jf<4;jf++){
            #pragma unroll
            for (int ir=0;ir<4;ir++){
                #pragma unroll
                for (int q=0;q<4;q++){
                    int j = w*64 + jf*16 + l4*4 + q;
                    int i = if4*64 + ir*16 + l15;
                    Sb[(size_t)j*264 + i] = f2bf(acc[jf][ir][q]);
                }
            }
        }
    }
}

// ---------------------------------------------------------------------------
// K6: states[p][n] = sum_j (coef_j*x[j,p]) * B[j,n]  via MFMA.
// 4 heads per block: BT (head-shared) staged once, amortized 4x.
// ---------------------------------------------------------------------------
__device__ __forceinline__ int swz264(int row, int col){
    return row*264 + (col ^ (((row>>3)&7)<<3));
}

__global__ __launch_bounds__(256) void ssd_states_mfma(
    const __hip_bfloat16* __restrict__ xbc,
    const float* __restrict__ dtp, const float* __restrict__ dAcs,
    float* __restrict__ states)
{
    __shared__ __align__(16) ushort_t xdT[64*264];
    __shared__ __align__(16) ushort_t BT[128*264];
    __shared__ float coef_s[CHUNK];
    int bc = blockIdx.x, hg = blockIdx.y;     // hg: 0..7 (head group of 4)
    int b = bc >> 3, c = bc & 7;
    int t = threadIdx.x;
    int l = t & 63, w = t >> 6;
    int l15 = l & 15, l4 = l >> 4;
    const ushort_t* xb = (const ushort_t*)xbc;
    const size_t rowbase = (size_t)bc*CHUNK*CONVDIM;

    // stage BT[n][j] = B[j][n] once (head-shared)
    #pragma unroll
    for (int ps=0; ps<16; ps++){
        int idx = ps*256 + t;
        int j = idx >> 4, n0 = (idx & 15)*8;
        bf16x8 v = *(const bf16x8*)&xb[rowbase + (size_t)j*CONVDIM + DINNER + n0];
        #pragma unroll
        for (int e=0;e<8;e++)
            BT[swz264(n0+e, j)] = ((const ushort_t*)&v)[e];
    }

    for (int hh=0; hh<4; hh++){
        int h = hg*4 + hh;
        size_t dbase = ((size_t)b*NHEADS + h)*L_N + c*CHUNK;
        float last = dAcs[dbase + CHUNK-1];
        float cf = __expf(last - dAcs[dbase + t]) * dtp[dbase + t];
        coef_s[t] = cf;
        __syncthreads();   // coef ready; prev-iter xdT readers done; BT ready (iter 0)

        // stage xdT[p][j] = coef_j * x[j][p]  (bf16, swizzled)
        #pragma unroll
        for (int ps=0; ps<8; ps++){
            int idx = ps*256 + t;
            int j = idx >> 3, p0 = (idx & 7)*8;
            float cj = coef_s[j];
            bf16x8 v = *(const bf16x8*)&xb[rowbase + (size_t)j*CONVDIM + h*HEADDIM + p0];
            #pragma unroll
            for (int e=0;e<8;e++)
                xdT[swz264(p0+e, j)] = f2bf(cj * bfbits2f(((const ushort_t*)&v)[e]));
        }
        __syncthreads();

        f32x4 acc[4][2];
        #pragma unroll
        for (int pf=0;pf<4;pf++){
            #pragma unroll
            for (int nf=0;nf<2;nf++) acc[pf][nf] = (f32x4){0.f,0.f,0.f,0.f};
        }

        #pragma unroll
        for (int k=0;k<8;k++){
            bf16x8 af[4], bv[2];
            #pragma unroll
            for (int pf=0;pf<4;pf++)
                af[pf] = *(const bf16x8*)&xdT[swz264(pf*16 + l15, k*32 + l4*8)];
            #pragma unroll
            for (int nf=0;nf<2;nf++)
                bv[nf] = *(const bf16x8*)&BT[swz264(w*32 + nf*16 + l15, k*32 + l4*8)];
            #pragma unroll
            for (int pf=0;pf<4;pf++){
                #pragma unroll
                for (int nf=0;nf<2;nf++)
                    acc[pf][nf] = __builtin_amdgcn_mfma_f32_16x16x32_bf16(af[pf], bv[nf], acc[pf][nf], 0, 0, 0);
            }
        }

        float* sb = states + (size_t)(bc*NHEADS + h)*HEADDIM*DSTATE;
        #pragma unroll
        for (int pf=0;pf<4;pf++){
            #pragma unroll
            for (int nf=0;nf<2;nf++){
                #pragma unroll
                for (int q=0;q<4;q++){
                    int p = pf*16 + l4*4 + q;
                    int n = w*32 + nf*16 + l15;
                    sb[(size_t)p*DSTATE + n] = acc[pf][nf][q];
                }
            }
        }
    }
}

// ---------------------------------------------------------------------------
// K7: inter-chunk scan (sequential over 8 chunks), in-place: states -> prev
// ---------------------------------------------------------------------------
__global__ __launch_bounds__(256) void scan_states(
    float* __restrict__ states, const float* __restrict__ dAcs)
{
    int idx = blockIdx.x*256 + threadIdx.x;
    int n  = idx & 127;
    int p  = (idx >> 7) & 63;
    int bh = idx >> 13;
    int b  = bh >> 5, h = bh & 31;
    float carry = 0.f;
    for (int c=0;c<NCHUNK;c++){
        size_t off = (((size_t)((b*NCHUNK + c)*NHEADS + h))*HEADDIM + p)*DSTATE + n;
        float s = states[off];
        states[off] = carry;
        float cd = __expf(dAcs[((size_t)b*NHEADS + h)*L_N + c*CHUNK + (CHUNK-1)]);
        carry = carry * cd + s;
    }
}

// ---------------------------------------------------------------------------
// K5: fused MFMA SSD: yh = exp(da_i)*(C@prev^T) + (W@x^T) + D*x  -> bf16 yh
// LDS diet: C-fragments and prev-fragments read direct from global (L2-hot).
// LDS = xdT + Ws + da/dt = 71.8 KB -> 2 blocks/CU.
// ---------------------------------------------------------------------------
__global__ __launch_bounds__(256) void ssd_mfma(
    const __hip_bfloat16* __restrict__ xbc,
    const float* __restrict__ dtp, const float* __restrict__ dAcs,
    const float* __restrict__ states, const ushort_t* __restrict__ S_T,
    const float* __restrict__ D_param, ushort_t* __restrict__ yh)
{
    __shared__ __align__(16) ushort_t Ws[256*72];    // 36 KB (wave-private rows)
    __shared__ __align__(16) ushort_t xdT[64*264];   // 33.8 KB
    __shared__ float da_s[CHUNK];
    __shared__ float dt_s[CHUNK];

    int bc = blockIdx.x, h = blockIdx.y;
    int b = bc >> 3, c = bc & 7;
    int t = threadIdx.x;
    int l = t & 63, w = t >> 6;
    int l15 = l & 15, l4 = l >> 4;

    const ushort_t* xb = (const ushort_t*)xbc;
    const size_t rowbase = (size_t)bc*CHUNK*CONVDIM;

    da_s[t] = dAcs[((size_t)b*NHEADS + h)*L_N + c*CHUNK + t];
    dt_s[t] = dtp[((size_t)b*NHEADS + h)*L_N + c*CHUNK + t];

    // stage x^T (cols h*64..): xdT[p][j] = x[j,p]
    #pragma unroll
    for (int ps=0; ps<8; ps++){
        int idx = ps*256 + t;
        int j = idx >> 3, p0 = (idx & 7)*8;
        bf16x8 v = *(const bf16x8*)&xb[rowbase + (size_t)j*CONVDIM + h*HEADDIM + p0];
        #pragma unroll
        for (int e=0;e<8;e++) xdT[(p0+e)*264 + j] = ((const ushort_t*)&v)[e];
    }
    __syncthreads();

    f32x4 yacc[4][4];
    #pragma unroll
    for (int m=0;m<4;m++){
        #pragma unroll
        for (int np=0;np<4;np++) yacc[m][np] = (f32x4){0.f,0.f,0.f,0.f};
    }

    // ---- Y_off = C @ prev^T, fragments direct from global (L2-hot)
    const ushort_t* cbase = xb + rowbase + (size_t)l15*CONVDIM + (DINNER+DSTATE) + l4*8;
    const float*    pbase = states + (size_t)(bc*NHEADS + h)*HEADDIM*DSTATE
                                   + (size_t)l15*DSTATE + l4*8;
    #pragma unroll
    for (int k=0;k<4;k++){
        bf16x8 bfk[4];
        #pragma unroll
        for (int np=0;np<4;np++){
            const float* pr = pbase + (size_t)(np*16)*DSTATE + k*32;
            float4 a = *(const float4*)pr;
            float4 bq = *(const float4*)(pr + 4);
            bf16x8 r;
            r[0]=(short)f2bf(a.x);  r[1]=(short)f2bf(a.y);
            r[2]=(short)f2bf(a.z);  r[3]=(short)f2bf(a.w);
            r[4]=(short)f2bf(bq.x); r[5]=(short)f2bf(bq.y);
            r[6]=(short)f2bf(bq.z); r[7]=(short)f2bf(bq.w);
            bfk[np] = r;
        }
        #pragma unroll
        for (int m=0;m<4;m++){
            int i0 = (m*4 + w)*16;
            bf16x8 af = *(const bf16x8*)(cbase + (size_t)i0*CONVDIM + k*32);
            #pragma unroll
            for (int np=0;np<4;np++)
                yacc[m][np] = __builtin_amdgcn_mfma_f32_16x16x32_bf16(af, bfk[np], yacc[m][np], 0, 0, 0);
        }
    }
    #pragma unroll
    for (int m=0;m<4;m++){
        int i0 = (m*4 + w)*16;
        #pragma unroll
        for (int q=0;q<4;q++){
            float e = __expf(da_s[i0 + l4*4 + q]);
            #pragma unroll
            for (int np=0;np<4;np++) yacc[m][np][q] *= e;
        }
    }

    // ---- Y_diag panels (no barriers: Ws rows wave-private, xdT read-only)
    const ushort_t* Sb = S_T + (size_t)bc*CHUNK*264;
    for (int jp=0; jp<4; jp++){
        bf16x8 bfx[4][2];
        #pragma unroll
        for (int np=0;np<4;np++){
            #pragma unroll
            for (int ks=0;ks<2;ks++)
                bfx[np][ks] = *(const bf16x8*)&xdT[(np*16 + l15)*264 + jp*64 + ks*32 + l4*8];
        }

        #pragma unroll
        for (int m=0;m<4;m++){
            int i0 = (m*4 + w)*16;
            int imax = i0 + 15;
            int kmaxY = (jp*64 <= imax ? 1 : 0) + (jp*64+32 <= imax ? 1 : 0);
            if (kmaxY == 0) continue;
            int nmax = 2*kmaxY;

            float dai[4];
            #pragma unroll
            for (int q=0;q<4;q++) dai[q] = da_s[i0 + l4*4 + q];
            #pragma unroll
            for (int n=0;n<4;n++){
                if (n < nmax){
                    int jcol = jp*64 + n*16 + l15;
                    float daj = da_s[jcol], dtj = dt_s[jcol];
                    ushort_t sv[4];
                    *(uint2*)sv = *(const uint2*)&Sb[(size_t)jcol*264 + i0 + l4*4];
                    #pragma unroll
                    for (int q=0;q<4;q++){
                        int i = i0 + l4*4 + q;
                        float wv = 0.f;
                        if (jcol <= i) wv = __expf(dai[q] - daj) * dtj * bfbits2f(sv[q]);
                        Ws[i*72 + n*16 + l15] = f2bf(wv);
                    }
                }
            }
            #pragma unroll
            for (int ks=0;ks<2;ks++){
                if (ks < kmaxY){
                    bf16x8 wfA = *(const bf16x8*)&Ws[(i0 + l15)*72 + ks*32 + l4*8];
                    #pragma unroll
                    for (int np=0;np<4;np++)
                        yacc[m][np] = __builtin_amdgcn_mfma_f32_16x16x32_bf16(wfA, bfx[np][ks], yacc[m][np], 0, 0, 0);
                }
            }
        }
    }

    // ---- epilogue: + D*x, store bf16
    float Dh = D_param[h];
    #pragma unroll
    for (int m=0;m<4;m++){
        int i0 = (m*4 + w)*16;
        #pragma unroll
        for (int np=0;np<4;np++){
            int p = np*16 + l15;
            #pragma unroll
            for (int q=0;q<4;q++){
                int i = i0 + l4*4 + q;
                float xv = bfbits2f(xdT[p*264 + i]);
                yh[((size_t)bc*CHUNK + i)*DINNER + h*HEADDIM + p] = f2bf(yacc[m][np][q] + Dh*xv);
            }
        }
    }
}

// ---------------------------------------------------------------------------
// K9: g = RMSNorm(yh * silu(z))*norm_w -> bf16 g  (vectorized, yh bf16)
// ---------------------------------------------------------------------------
__global__ __launch_bounds__(256) void gate_norm(
    const ushort_t* __restrict__ yh, const __hip_bfloat16* __restrict__ z,
    const float* __restrict__ norm_w, __hip_bfloat16* __restrict__ g)
{
    int row = blockIdx.x;
    int t = threadIdx.x;
    const ushort_t* yr = yh + (size_t)row*DINNER + t*8;
    const ushort_t* zr = (const ushort_t*)z + (size_t)row*DINNER + t*8;
    bf16x8 yv = *(const bf16x8*)yr;
    bf16x8 zv8 = *(const bf16x8*)zr;
    float v[8];
    float ss = 0.f;
    #pragma unroll
    for (int e=0;e<8;e++){
        float y = bfbits2f(((const ushort_t*)&yv)[e]);
        float zz = bfbits2f(((const ushort_t*)&zv8)[e]);
        float gv = y * (zz / (1.f + __expf(-zz)));
        v[e] = gv; ss += gv*gv;
    }
    #pragma unroll
    for (int off=32; off>=1; off>>=1) ss += __shfl_xor(ss, off);
    __shared__ float red[4];
    if ((t & 63) == 0) red[t >> 6] = ss;
    __syncthreads();
    float tot = red[0]+red[1]+red[2]+red[3];
    float scale = rsqrtf(tot * (1.f/DINNER) + 1e-5f);
    float4 w0 = *(const float4*)&norm_w[t*8];
    float4 w1 = *(const float4*)&norm_w[t*8+4];
    float nw[8] = {w0.x,w0.y,w0.z,w0.w,w1.x,w1.y,w1.z,w1.w};
    ushort_t o[8];
    #pragma unroll
    for (int e=0;e<8;e++) o[e] = f2bf(v[e]*scale*nw[e]);
    *(uint4*)((ushort_t*)g + (size_t)row*DINNER + t*8) = *(const uint4*)o;
}

// ---------------------------------------------------------------------------
extern "C" void kernel_launch(void* const* d_in, const int* in_sizes, int n_in,
                              void* d_out, int out_size, void* d_ws, size_t ws_size,
                              hipStream_t stream)
{
    const float* u       = (const float*)d_in[0];
    const float* W_in    = (const float*)d_in[1];
    const float* conv_w  = (const float*)d_in[2];
    const float* conv_b  = (const float*)d_in[3];
    const float* dt_bias = (const float*)d_in[4];
    const float* A_log   = (const float*)d_in[5];
    const float* D_param = (const float*)d_in[6];
    const float* norm_w  = (const float*)d_in[7];
    const float* W_out   = (const float*)d_in[8];
    float* out = (float*)d_out;

    char* p = (char*)d_ws;
    auto take = [&](size_t n){ char* r = p; p += (n + 255) & ~(size_t)255; return r; };

    __hip_bfloat16* z       = (__hip_bfloat16*)take((size_t)BL*DINNER*2);
    __hip_bfloat16* xbc_raw = (__hip_bfloat16*)take((size_t)BL*CONVDIM*2);
    __hip_bfloat16* xbc     = (__hip_bfloat16*)take((size_t)BL*CONVDIM*2);
    float* dtp     = (float*)take((size_t)BL*NHEADS*4);
    float* dAcs    = (float*)take((size_t)BL*NHEADS*4);
    float* states  = (float*)take((size_t)B_N*NCHUNK*NHEADS*HEADDIM*DSTATE*4);
    ushort_t* yh   = (ushort_t*)take((size_t)BL*DINNER*2);
    ushort_t* S_T  = (ushort_t*)take((size_t)B_N*NCHUNK*CHUNK*264*2);
    ushort_t* u_bf  = (ushort_t*)take((size_t)BL*DMODEL*2);
    ushort_t* Wi_bf = (ushort_t*)take((size_t)DINPROJ*DMODEL*2);
    ushort_t* Wo_bf = (ushort_t*)take((size_t)DMODEL*DINNER*2);
    float* wT       = (float*)take((size_t)DCONV*CONVDIM*4);
    __hip_bfloat16* g = z;   // alias: z dead after gate_norm's elementwise read

    cvt_bf16<<<dim3((BL*DMODEL/8 + 255)/256), 256, 0, stream>>>(u, u_bf, BL*DMODEL/8);
    cvt_bf16<<<dim3((DINPROJ*DMODEL/8 + 255)/256), 256, 0, stream>>>(W_in, Wi_bf, DINPROJ*DMODEL/8);
    cvt_bf16<<<dim3((DMODEL*DINNER/8 + 255)/256), 256, 0, stream>>>(W_out, Wo_bf, DMODEL*DINNER/8);
    cvt_wT<<<dim3((CONVDIM+255)/256), 256, 0, stream>>>(conv_w, wT);

    // in-proj: z + xBC + dt (N = 4480 = 35 * 128, cols >=4384 dropped)
    gemm_bt_mfma<DMODEL,35,1><<<dim3(64*35), 256, 0, stream>>>(
        u_bf, Wi_bf, nullptr, (ushort_t*)z, (ushort_t*)xbc_raw, dt_bias, dtp);

    conv_silu<<<dim3(BL*(CONVDIM/8)/256), 256, 0, stream>>>(xbc_raw, wT, conv_b, xbc);
    dt_cumsum<<<dim3(B_N*NHEADS*NCHUNK), 256, 0, stream>>>(dtp, A_log, dAcs);
    bc_scores_mfma<<<dim3(B_N*NCHUNK), 256, 0, stream>>>(xbc, S_T);
    ssd_states_mfma<<<dim3(B_N*NCHUNK, NHEADS/4), 256, 0, stream>>>(xbc, dtp, dAcs, states);
    scan_states<<<dim3((B_N*NHEADS*HEADDIM*DSTATE)/256), 256, 0, stream>>>(states, dAcs);
    ssd_mfma<<<dim3(B_N*NCHUNK, NHEADS), 256, 0, stream>>>(xbc, dtp, dAcs, states, S_T, D_param, yh);
    gate_norm<<<dim3(BL), 256, 0, stream>>>(yh, z, norm_w, g);

    // out-proj
    gemm_bt_mfma<DINNER,8,0><<<dim3(64*8), 256, 0, stream>>>(
        (const ushort_t*)g, Wo_bf, out, nullptr, nullptr, nullptr, nullptr);
}